// Round 5
// baseline (4521.814 us; speedup 1.0000x reference)
//
#include <hip/hip_runtime.h>
#include <hip/hip_bf16.h>
#include <math.h>

// BiMambaBlock: B=8, L=2048, D_MODEL=256, D_INNER=512, N=16, DT_RANK=16, D_CONV=4
// fp32 baseline, dt_proj fused into the scan.
//
// Per direction (dir=0 fwd, dir=1 bwd; bwd works in flipped-time local coords):
//  1) in_proj GEMM: xz = x[flip?] @ W_in^T -> U (cols 0..511), Z (512..1023)
//  2) causal depthwise conv4 + bias + silu: U -> UC
//  3) x_proj GEMM: UC @ W_x^T -> DTR(16) | BB(16) | CB(16)
//  4) selective scan with fused dt_proj+softplus (16 lanes per (b,d);
//     lane n holds state n and Wdt[d,n]; two 4-step shfl reduces per t:
//     dt-dot and C-dot) + *silu(Z) -> Y (reuses U)
//  5) out_proj GEMM: out[flip?] (+)= Y @ W_out^T (+x residual on dir 0)
// Then LayerNorm in-place on out.
// Workspace: U,Z,UC (3 x 33.5MB) + DTR,BB,CB (3 x 1MB) ~= 104MB.

#define TOK 16384      // B*L
#define LSEQ 2048
#define DI 512
#define DM 256
#define NST 16

__device__ __forceinline__ float fast_exp2(float x) {
#if defined(__has_builtin)
#if __has_builtin(__builtin_amdgcn_exp2f)
  return __builtin_amdgcn_exp2f(x);
#else
  return exp2f(x);
#endif
#else
  return exp2f(x);
#endif
}

__device__ __forceinline__ float silu_f(float v) {
  return v / (1.f + __expf(-v));
}

// ---------------- in_proj GEMM: M=16384, N=1024, K=256 ----------------
__global__ __launch_bounds__(256) void gemm_inproj(
    const float* __restrict__ X, const float* __restrict__ W,
    float* __restrict__ U, float* __restrict__ Z, int dir) {
  __shared__ float As[16][132];
  __shared__ float Bs[16][132];
  const int tid = threadIdx.x;
  const int tx = tid & 15, ty = tid >> 4;
  const int bm = blockIdx.y * 128, bn = blockIdx.x * 128;
  const int lr = tid >> 2;          // 0..63
  const int lk = (tid & 3) * 4;     // 0,4,8,12
  float acc[8][8] = {};
  for (int k0 = 0; k0 < 256; k0 += 16) {
#pragma unroll
    for (int h = 0; h < 2; ++h) {
      int tl = bm + lr + h * 64;
      int bidx = tl >> 11, tp = tl & 2047;
      int src = (bidx << 11) + (dir ? (2047 - tp) : tp);
      float4 v = *reinterpret_cast<const float4*>(X + (size_t)src * 256 + k0 + lk);
      As[lk + 0][lr + h * 64] = v.x;
      As[lk + 1][lr + h * 64] = v.y;
      As[lk + 2][lr + h * 64] = v.z;
      As[lk + 3][lr + h * 64] = v.w;
    }
#pragma unroll
    for (int h = 0; h < 2; ++h) {
      int wr = bn + lr + h * 64;
      float4 v = *reinterpret_cast<const float4*>(W + (size_t)wr * 256 + k0 + lk);
      Bs[lk + 0][lr + h * 64] = v.x;
      Bs[lk + 1][lr + h * 64] = v.y;
      Bs[lk + 2][lr + h * 64] = v.z;
      Bs[lk + 3][lr + h * 64] = v.w;
    }
    __syncthreads();
#pragma unroll
    for (int k = 0; k < 16; ++k) {
      float4 a0 = *reinterpret_cast<const float4*>(&As[k][ty * 8]);
      float4 a1 = *reinterpret_cast<const float4*>(&As[k][ty * 8 + 4]);
      float4 b0 = *reinterpret_cast<const float4*>(&Bs[k][tx * 8]);
      float4 b1 = *reinterpret_cast<const float4*>(&Bs[k][tx * 8 + 4]);
      float a[8] = {a0.x, a0.y, a0.z, a0.w, a1.x, a1.y, a1.z, a1.w};
      float b[8] = {b0.x, b0.y, b0.z, b0.w, b1.x, b1.y, b1.z, b1.w};
#pragma unroll
      for (int i = 0; i < 8; ++i)
#pragma unroll
        for (int j = 0; j < 8; ++j) acc[i][j] = fmaf(a[i], b[j], acc[i][j]);
    }
    __syncthreads();
  }
#pragma unroll
  for (int i = 0; i < 8; ++i) {
    int row = bm + ty * 8 + i;
#pragma unroll
    for (int j = 0; j < 8; j += 4) {
      int col = bn + tx * 8 + j;
      float4 v = {acc[i][j], acc[i][j + 1], acc[i][j + 2], acc[i][j + 3]};
      if (col < DI)
        *reinterpret_cast<float4*>(U + (size_t)row * DI + col) = v;
      else
        *reinterpret_cast<float4*>(Z + (size_t)row * DI + (col - DI)) = v;
    }
  }
}

// ---------------- causal depthwise conv4 + bias + silu ----------------
__global__ __launch_bounds__(256) void conv_kernel(
    const float* __restrict__ U, const float* __restrict__ CW,
    const float* __restrict__ CB, float* __restrict__ UC) {
  int idx = blockIdx.x * 256 + threadIdx.x;
  int tl = idx >> 9, d = idx & 511;
  int tp = tl & 2047;
  float4 w4 = *reinterpret_cast<const float4*>(CW + (size_t)d * 4);
  float u3 = U[idx];
  float u2 = (tp >= 1) ? U[idx - 512] : 0.f;
  float u1 = (tp >= 2) ? U[idx - 1024] : 0.f;
  float u0 = (tp >= 3) ? U[idx - 1536] : 0.f;
  float acc = CB[d] + w4.x * u0 + w4.y * u1 + w4.z * u2 + w4.w * u3;
  UC[idx] = silu_f(acc);
}

// ---------------- x_proj GEMM: M=16384, N=48, K=512 ----------------
__global__ __launch_bounds__(256) void gemm_xproj(
    const float* __restrict__ UC, const float* __restrict__ W,
    float* __restrict__ DTR, float* __restrict__ BB, float* __restrict__ CB) {
  __shared__ float As[32][68];
  __shared__ float Ws[32][52];
  const int tid = threadIdx.x;
  const int bm = blockIdx.x * 64;
  const int tx = tid & 15, ty = tid >> 4;
  float acc[4][3] = {};
  for (int k0 = 0; k0 < 512; k0 += 32) {
#pragma unroll
    for (int h = 0; h < 2; ++h) {
      int f = tid + h * 256;
      int r = f >> 3, kk = (f & 7) * 4;
      float4 v = *reinterpret_cast<const float4*>(UC + (size_t)(bm + r) * DI + k0 + kk);
      As[kk + 0][r] = v.x;
      As[kk + 1][r] = v.y;
      As[kk + 2][r] = v.z;
      As[kk + 3][r] = v.w;
    }
    {
      int f = tid;
      int r = f >> 3, kk = (f & 7) * 4;
      float4 v = *reinterpret_cast<const float4*>(W + (size_t)r * DI + k0 + kk);
      Ws[kk + 0][r] = v.x;
      Ws[kk + 1][r] = v.y;
      Ws[kk + 2][r] = v.z;
      Ws[kk + 3][r] = v.w;
    }
    if (tid < 128) {
      int f = tid + 256;
      int r = f >> 3, kk = (f & 7) * 4;
      float4 v = *reinterpret_cast<const float4*>(W + (size_t)r * DI + k0 + kk);
      Ws[kk + 0][r] = v.x;
      Ws[kk + 1][r] = v.y;
      Ws[kk + 2][r] = v.z;
      Ws[kk + 3][r] = v.w;
    }
    __syncthreads();
#pragma unroll
    for (int k = 0; k < 32; ++k) {
      float a[4], w[3];
#pragma unroll
      for (int i = 0; i < 4; ++i) a[i] = As[k][ty * 4 + i];
#pragma unroll
      for (int j = 0; j < 3; ++j) w[j] = Ws[k][tx * 3 + j];
#pragma unroll
      for (int i = 0; i < 4; ++i)
#pragma unroll
        for (int j = 0; j < 3; ++j) acc[i][j] = fmaf(a[i], w[j], acc[i][j]);
    }
    __syncthreads();
  }
#pragma unroll
  for (int i = 0; i < 4; ++i) {
    int row = bm + ty * 4 + i;
#pragma unroll
    for (int j = 0; j < 3; ++j) {
      int c = tx * 3 + j;
      float* dst = (c < 16) ? DTR : (c < 32) ? BB : CB;
      dst[(size_t)row * 16 + (c & 15)] = acc[i][j];
    }
  }
}

// ---------------- selective scan with fused dt_proj ----------------
// 16 lanes per (b,d) pair; lane n owns state n and Wdt[d,n].
// Per t: dt = softplus(bdt[d] + sum_n DTR[b,t,n]*Wdt[d,n]) via shfl reduce,
// then h_n = exp(dt*A_n)*h_n + dt*B_n*u; y = sum_n h_n*C_n via shfl reduce.
__global__ __launch_bounds__(256) void scan_kernel(
    const float* __restrict__ UC, const float* __restrict__ DTR,
    const float* __restrict__ Wdt, const float* __restrict__ bdt,
    const float* __restrict__ Z, const float* __restrict__ BB,
    const float* __restrict__ CB, const float* __restrict__ Alog,
    const float* __restrict__ Dp, float* __restrict__ Y) {
  const int tid = threadIdx.x;
  const int g = blockIdx.x * 16 + (tid >> 4);  // b*512 + d
  const int n = tid & 15;
  const int b = g >> 9, d = g & 511;
  const float A2 = -__expf(Alog[d * 16 + n]) * 1.44269504f;  // A*log2(e)
  const float wdt_n = Wdt[d * 16 + n];
  const float bias = bdt[d];
  const float Dd = Dp[d];
  const size_t base = (size_t)b * LSEQ * DI + d;
  const float* up = UC + base;
  const float* zp = Z + base;
  float* yp = Y + base;
  const size_t nbase = (size_t)b * LSEQ * 16 + n;
  const float* dtrp = DTR + nbase;
  const float* Bp = BB + nbase;
  const float* Cp = CB + nbase;
  float h = 0.f;
#pragma unroll 4
  for (int t = 0; t < LSEQ; ++t) {
    float uv = up[(size_t)t * DI];
    float Bv = Bp[(size_t)t * 16];
    float Cv = Cp[(size_t)t * 16];
    // fused dt_proj: 16-lane dot of DTR row with Wdt[d,:]
    float p = dtrp[(size_t)t * 16] * wdt_n;
    p += __shfl_xor(p, 1);
    p += __shfl_xor(p, 2);
    p += __shfl_xor(p, 4);
    p += __shfl_xor(p, 8);
    float sdt = p + bias;
    float dtv = (sdt > 20.f) ? sdt : log1pf(__expf(sdt));
    float dA = fast_exp2(dtv * A2);
    h = fmaf(dA, h, dtv * Bv * uv);
    float s = h * Cv;
    s += __shfl_xor(s, 1);
    s += __shfl_xor(s, 2);
    s += __shfl_xor(s, 4);
    s += __shfl_xor(s, 8);
    if (n == 0) {
      float zv = zp[(size_t)t * DI];
      yp[(size_t)t * DI] = (s + Dd * uv) * silu_f(zv);
    }
  }
}

// ---------------- out_proj GEMM: M=16384, N=256, K=512 (+residual, +=) ----------------
__global__ __launch_bounds__(256) void gemm_outproj(
    const float* __restrict__ Y, const float* __restrict__ W,
    const float* __restrict__ X, float* __restrict__ Out, int dir) {
  __shared__ float As[16][132];
  __shared__ float Bs[16][132];
  const int tid = threadIdx.x;
  const int tx = tid & 15, ty = tid >> 4;
  const int bm = blockIdx.y * 128, bn = blockIdx.x * 128;
  const int lr = tid >> 2;
  const int lk = (tid & 3) * 4;
  float acc[8][8] = {};
  for (int k0 = 0; k0 < 512; k0 += 16) {
#pragma unroll
    for (int h = 0; h < 2; ++h) {
      int tl = bm + lr + h * 64;
      float4 v = *reinterpret_cast<const float4*>(Y + (size_t)tl * DI + k0 + lk);
      As[lk + 0][lr + h * 64] = v.x;
      As[lk + 1][lr + h * 64] = v.y;
      As[lk + 2][lr + h * 64] = v.z;
      As[lk + 3][lr + h * 64] = v.w;
    }
#pragma unroll
    for (int h = 0; h < 2; ++h) {
      int wr = bn + lr + h * 64;
      float4 v = *reinterpret_cast<const float4*>(W + (size_t)wr * DI + k0 + lk);
      Bs[lk + 0][lr + h * 64] = v.x;
      Bs[lk + 1][lr + h * 64] = v.y;
      Bs[lk + 2][lr + h * 64] = v.z;
      Bs[lk + 3][lr + h * 64] = v.w;
    }
    __syncthreads();
#pragma unroll
    for (int k = 0; k < 16; ++k) {
      float4 a0 = *reinterpret_cast<const float4*>(&As[k][ty * 8]);
      float4 a1 = *reinterpret_cast<const float4*>(&As[k][ty * 8 + 4]);
      float4 b0 = *reinterpret_cast<const float4*>(&Bs[k][tx * 8]);
      float4 b1 = *reinterpret_cast<const float4*>(&Bs[k][tx * 8 + 4]);
      float a[8] = {a0.x, a0.y, a0.z, a0.w, a1.x, a1.y, a1.z, a1.w};
      float b[8] = {b0.x, b0.y, b0.z, b0.w, b1.x, b1.y, b1.z, b1.w};
#pragma unroll
      for (int i = 0; i < 8; ++i)
#pragma unroll
        for (int j = 0; j < 8; ++j) acc[i][j] = fmaf(a[i], b[j], acc[i][j]);
    }
    __syncthreads();
  }
#pragma unroll
  for (int i = 0; i < 8; ++i) {
    int tl = bm + ty * 8 + i;
    int bidx = tl >> 11, tp = tl & 2047;
    int orow = (bidx << 11) + (dir ? (2047 - tp) : tp);
#pragma unroll
    for (int j = 0; j < 8; j += 4) {
      int col = bn + tx * 8 + j;
      float4 v = {acc[i][j], acc[i][j + 1], acc[i][j + 2], acc[i][j + 3]};
      float4* dst = reinterpret_cast<float4*>(Out + (size_t)orow * DM + col);
      if (dir == 0) {
        float4 r = *reinterpret_cast<const float4*>(X + (size_t)orow * DM + col);
        v.x += r.x; v.y += r.y; v.z += r.z; v.w += r.w;
        *dst = v;
      } else {
        float4 o = *dst;
        o.x += v.x; o.y += v.y; o.z += v.z; o.w += v.w;
        *dst = o;
      }
    }
  }
}

// ---------------- LayerNorm in-place ----------------
__global__ __launch_bounds__(256) void ln_kernel(
    float* __restrict__ H, const float* __restrict__ G, const float* __restrict__ Be) {
  const int lane = threadIdx.x & 63;
  const int row = blockIdx.x * 4 + (threadIdx.x >> 6);
  float4 v = *reinterpret_cast<const float4*>(H + (size_t)row * DM + lane * 4);
  float s = v.x + v.y + v.z + v.w;
  float sq = v.x * v.x + v.y * v.y + v.z * v.z + v.w * v.w;
#pragma unroll
  for (int m = 32; m >= 1; m >>= 1) {
    s += __shfl_xor(s, m);
    sq += __shfl_xor(sq, m);
  }
  float mu = s * (1.f / 256.f);
  float var = sq * (1.f / 256.f) - mu * mu;
  float inv = rsqrtf(var + 1e-5f);
  float4 g = *reinterpret_cast<const float4*>(G + lane * 4);
  float4 be = *reinterpret_cast<const float4*>(Be + lane * 4);
  float4 o;
  o.x = (v.x - mu) * inv * g.x + be.x;
  o.y = (v.y - mu) * inv * g.y + be.y;
  o.z = (v.z - mu) * inv * g.z + be.z;
  o.w = (v.w - mu) * inv * g.w + be.w;
  *reinterpret_cast<float4*>(H + (size_t)row * DM + lane * 4) = o;
}

extern "C" void kernel_launch(void* const* d_in, const int* in_sizes, int n_in,
                              void* d_out, int out_size, void* d_ws, size_t ws_size,
                              hipStream_t stream) {
  const float* x = (const float*)d_in[0];
  const float* ln_g = (const float*)d_in[19];
  const float* ln_b = (const float*)d_in[20];
  float* out = (float*)d_out;
  float* ws = (float*)d_ws;

  float* U = ws;                       // 16384*512
  float* Z = U + (size_t)TOK * DI;     // 16384*512
  float* UC = Z + (size_t)TOK * DI;    // 16384*512
  float* DTR = UC + (size_t)TOK * DI;  // 16384*16
  float* BB = DTR + (size_t)TOK * 16;  // 16384*16
  float* CB = BB + (size_t)TOK * 16;   // 16384*16

  for (int dir = 0; dir < 2; ++dir) {
    const float* Win = (const float*)d_in[1 + dir * 9];
    const float* cw = (const float*)d_in[2 + dir * 9];
    const float* cb = (const float*)d_in[3 + dir * 9];
    const float* Wx = (const float*)d_in[4 + dir * 9];
    const float* Wdt = (const float*)d_in[5 + dir * 9];
    const float* bdt = (const float*)d_in[6 + dir * 9];
    const float* Alog = (const float*)d_in[7 + dir * 9];
    const float* Dp = (const float*)d_in[8 + dir * 9];
    const float* Wout = (const float*)d_in[9 + dir * 9];

    gemm_inproj<<<dim3(8, 128), 256, 0, stream>>>(x, Win, U, Z, dir);
    conv_kernel<<<(TOK * DI) / 256, 256, 0, stream>>>(U, cw, cb, UC);
    gemm_xproj<<<TOK / 64, 256, 0, stream>>>(UC, Wx, DTR, BB, CB);
    scan_kernel<<<(8 * DI) / 16, 256, 0, stream>>>(UC, DTR, Wdt, bdt, Z, BB, CB, Alog, Dp, U);
    gemm_outproj<<<dim3(2, 128), 256, 0, stream>>>(U, Wout, x, out, dir);
  }
  ln_kernel<<<TOK / 4, 256, 0, stream>>>(out, ln_g, ln_b);
}

// Round 9
// 849.787 us; speedup vs baseline: 5.3211x; 5.3211x over previous
//
#include <hip/hip_runtime.h>
#include <hip/hip_bf16.h>
#include <math.h>

// BiMambaBlock: B=8, L=2048, D_MODEL=256, D_INNER=512, N=16, DT_RANK=16, D_CONV=4
// fp32; chunked 3-pass selective scan (32 chunks x 64 steps).
//
// Per direction (dir=0 fwd, dir=1 bwd; bwd works in flipped-time local coords):
//  1) in_proj GEMM: xz = x[flip?] @ W_in^T -> U (cols 0..511), Z (512..1023)
//  2) causal depthwise conv4 + bias + silu: U -> UC   (U dead afterwards)
//  3) x_proj GEMM: UC @ W_x^T -> DTR(16) | BB(16) | CB(16)
//  4) scan_pass1: per (b,chunk,d) thread, 16 states in regs, dt_proj in-reg;
//     local scan seed 0 over 64 steps -> APR (prod dA), HLOC (end state).
//     APR/HLOC live in U's storage (16.8 MB).
//  5) scan_pass2: per (b,d,n) serial carry over 32 chunks; HLOC <- seed.
//  6) scan_pass3: replay chunk seeded; y=(sum h*C + D*u)*silu(z) written
//     IN-PLACE over UC (each element written by its only reader).
//  7) out_proj GEMM: out[flip?] (+)= Y @ W_out^T (+x residual on dir 0)
// Then LayerNorm in-place on out.  Workspace ~104 MB (same as proven layout).

#define TOK 16384      // B*L
#define LSEQ 2048
#define DI 512
#define DM 256
#define NST 16
#define NCH 32         // chunks
#define CHT 64         // steps per chunk

__device__ __forceinline__ float fast_exp2(float x) {
#if defined(__has_builtin)
#if __has_builtin(__builtin_amdgcn_exp2f)
  return __builtin_amdgcn_exp2f(x);
#else
  return exp2f(x);
#endif
#else
  return exp2f(x);
#endif
}

__device__ __forceinline__ float silu_f(float v) {
  return v / (1.f + __expf(-v));
}

__device__ __forceinline__ float softplus_f(float s) {
  return (s > 20.f) ? s : log1pf(__expf(s));
}

// ---------------- in_proj GEMM: M=16384, N=1024, K=256 ----------------
__global__ __launch_bounds__(256) void gemm_inproj(
    const float* __restrict__ X, const float* __restrict__ W,
    float* __restrict__ U, float* __restrict__ Z, int dir) {
  __shared__ float As[16][132];
  __shared__ float Bs[16][132];
  const int tid = threadIdx.x;
  const int tx = tid & 15, ty = tid >> 4;
  const int bm = blockIdx.y * 128, bn = blockIdx.x * 128;
  const int lr = tid >> 2;          // 0..63
  const int lk = (tid & 3) * 4;     // 0,4,8,12
  float acc[8][8] = {};
  for (int k0 = 0; k0 < 256; k0 += 16) {
#pragma unroll
    for (int h = 0; h < 2; ++h) {
      int tl = bm + lr + h * 64;
      int bidx = tl >> 11, tp = tl & 2047;
      int src = (bidx << 11) + (dir ? (2047 - tp) : tp);
      float4 v = *reinterpret_cast<const float4*>(X + (size_t)src * 256 + k0 + lk);
      As[lk + 0][lr + h * 64] = v.x;
      As[lk + 1][lr + h * 64] = v.y;
      As[lk + 2][lr + h * 64] = v.z;
      As[lk + 3][lr + h * 64] = v.w;
    }
#pragma unroll
    for (int h = 0; h < 2; ++h) {
      int wr = bn + lr + h * 64;
      float4 v = *reinterpret_cast<const float4*>(W + (size_t)wr * 256 + k0 + lk);
      Bs[lk + 0][lr + h * 64] = v.x;
      Bs[lk + 1][lr + h * 64] = v.y;
      Bs[lk + 2][lr + h * 64] = v.z;
      Bs[lk + 3][lr + h * 64] = v.w;
    }
    __syncthreads();
#pragma unroll
    for (int k = 0; k < 16; ++k) {
      float4 a0 = *reinterpret_cast<const float4*>(&As[k][ty * 8]);
      float4 a1 = *reinterpret_cast<const float4*>(&As[k][ty * 8 + 4]);
      float4 b0 = *reinterpret_cast<const float4*>(&Bs[k][tx * 8]);
      float4 b1 = *reinterpret_cast<const float4*>(&Bs[k][tx * 8 + 4]);
      float a[8] = {a0.x, a0.y, a0.z, a0.w, a1.x, a1.y, a1.z, a1.w};
      float b[8] = {b0.x, b0.y, b0.z, b0.w, b1.x, b1.y, b1.z, b1.w};
#pragma unroll
      for (int i = 0; i < 8; ++i)
#pragma unroll
        for (int j = 0; j < 8; ++j) acc[i][j] = fmaf(a[i], b[j], acc[i][j]);
    }
    __syncthreads();
  }
#pragma unroll
  for (int i = 0; i < 8; ++i) {
    int row = bm + ty * 8 + i;
#pragma unroll
    for (int j = 0; j < 8; j += 4) {
      int col = bn + tx * 8 + j;
      float4 v = {acc[i][j], acc[i][j + 1], acc[i][j + 2], acc[i][j + 3]};
      if (col < DI)
        *reinterpret_cast<float4*>(U + (size_t)row * DI + col) = v;
      else
        *reinterpret_cast<float4*>(Z + (size_t)row * DI + (col - DI)) = v;
    }
  }
}

// ---------------- causal depthwise conv4 + bias + silu ----------------
__global__ __launch_bounds__(256) void conv_kernel(
    const float* __restrict__ U, const float* __restrict__ CW,
    const float* __restrict__ CB, float* __restrict__ UC) {
  int idx = blockIdx.x * 256 + threadIdx.x;
  int tl = idx >> 9, d = idx & 511;
  int tp = tl & 2047;
  float4 w4 = *reinterpret_cast<const float4*>(CW + (size_t)d * 4);
  float u3 = U[idx];
  float u2 = (tp >= 1) ? U[idx - 512] : 0.f;
  float u1 = (tp >= 2) ? U[idx - 1024] : 0.f;
  float u0 = (tp >= 3) ? U[idx - 1536] : 0.f;
  float acc = CB[d] + w4.x * u0 + w4.y * u1 + w4.z * u2 + w4.w * u3;
  UC[idx] = silu_f(acc);
}

// ---------------- x_proj GEMM: M=16384, N=48, K=512 ----------------
__global__ __launch_bounds__(256) void gemm_xproj(
    const float* __restrict__ UC, const float* __restrict__ W,
    float* __restrict__ DTR, float* __restrict__ BB, float* __restrict__ CB) {
  __shared__ float As[32][68];
  __shared__ float Ws[32][52];
  const int tid = threadIdx.x;
  const int bm = blockIdx.x * 64;
  const int tx = tid & 15, ty = tid >> 4;
  float acc[4][3] = {};
  for (int k0 = 0; k0 < 512; k0 += 32) {
#pragma unroll
    for (int h = 0; h < 2; ++h) {
      int f = tid + h * 256;
      int r = f >> 3, kk = (f & 7) * 4;
      float4 v = *reinterpret_cast<const float4*>(UC + (size_t)(bm + r) * DI + k0 + kk);
      As[kk + 0][r] = v.x;
      As[kk + 1][r] = v.y;
      As[kk + 2][r] = v.z;
      As[kk + 3][r] = v.w;
    }
    {
      int f = tid;
      int r = f >> 3, kk = (f & 7) * 4;
      float4 v = *reinterpret_cast<const float4*>(W + (size_t)r * DI + k0 + kk);
      Ws[kk + 0][r] = v.x;
      Ws[kk + 1][r] = v.y;
      Ws[kk + 2][r] = v.z;
      Ws[kk + 3][r] = v.w;
    }
    if (tid < 128) {
      int f = tid + 256;
      int r = f >> 3, kk = (f & 7) * 4;
      float4 v = *reinterpret_cast<const float4*>(W + (size_t)r * DI + k0 + kk);
      Ws[kk + 0][r] = v.x;
      Ws[kk + 1][r] = v.y;
      Ws[kk + 2][r] = v.z;
      Ws[kk + 3][r] = v.w;
    }
    __syncthreads();
#pragma unroll
    for (int k = 0; k < 32; ++k) {
      float a[4], w[3];
#pragma unroll
      for (int i = 0; i < 4; ++i) a[i] = As[k][ty * 4 + i];
#pragma unroll
      for (int j = 0; j < 3; ++j) w[j] = Ws[k][tx * 3 + j];
#pragma unroll
      for (int i = 0; i < 4; ++i)
#pragma unroll
        for (int j = 0; j < 3; ++j) acc[i][j] = fmaf(a[i], w[j], acc[i][j]);
    }
    __syncthreads();
  }
#pragma unroll
  for (int i = 0; i < 4; ++i) {
    int row = bm + ty * 4 + i;
#pragma unroll
    for (int j = 0; j < 3; ++j) {
      int c = tx * 3 + j;
      float* dst = (c < 16) ? DTR : (c < 32) ? BB : CB;
      dst[(size_t)row * 16 + (c & 15)] = acc[i][j];
    }
  }
}

// ---------------- scan pass 1: per-chunk local scan + dA product ----------------
// block: b = blk>>6, chunk c = (blk&63)>>1, d = (blk&1)*256 + tid.
__global__ __launch_bounds__(256) void scan_pass1(
    const float* __restrict__ UC, const float* __restrict__ DTR,
    const float* __restrict__ Wdt, const float* __restrict__ bdt,
    const float* __restrict__ BB, const float* __restrict__ Alog,
    float* __restrict__ APR, float* __restrict__ HLOC) {
  const int blk = blockIdx.x;
  const int b = blk >> 6;
  const int r = blk & 63;
  const int c = r >> 1;
  const int d = (r & 1) * 256 + threadIdx.x;
  float w[16], A2[16], h[16], ap[16];
  {
    const float4* w4 = reinterpret_cast<const float4*>(Wdt + (size_t)d * 16);
    const float4* a4 = reinterpret_cast<const float4*>(Alog + (size_t)d * 16);
#pragma unroll
    for (int q = 0; q < 4; ++q) {
      float4 v = w4[q];
      w[q * 4] = v.x; w[q * 4 + 1] = v.y; w[q * 4 + 2] = v.z; w[q * 4 + 3] = v.w;
      float4 a = a4[q];
      A2[q * 4]     = -__expf(a.x) * 1.44269504f;
      A2[q * 4 + 1] = -__expf(a.y) * 1.44269504f;
      A2[q * 4 + 2] = -__expf(a.z) * 1.44269504f;
      A2[q * 4 + 3] = -__expf(a.w) * 1.44269504f;
    }
  }
  const float bias = bdt[d];
#pragma unroll
  for (int n = 0; n < 16; ++n) { h[n] = 0.f; ap[n] = 1.f; }
  const int t0 = c * CHT;
  for (int tt = 0; tt < CHT; ++tt) {
    const size_t row = (size_t)b * LSEQ + (t0 + tt);
    const float4* dtr4 = reinterpret_cast<const float4*>(DTR + row * 16);
    const float4* bb4 = reinterpret_cast<const float4*>(BB + row * 16);
    float4 d0 = dtr4[0], d1 = dtr4[1], d2 = dtr4[2], d3 = dtr4[3];
    float4 b0 = bb4[0], b1 = bb4[1], b2 = bb4[2], b3 = bb4[3];
    float uv = UC[row * DI + d];
    float sdt = bias
      + d0.x * w[0] + d0.y * w[1] + d0.z * w[2] + d0.w * w[3]
      + d1.x * w[4] + d1.y * w[5] + d1.z * w[6] + d1.w * w[7]
      + d2.x * w[8] + d2.y * w[9] + d2.z * w[10] + d2.w * w[11]
      + d3.x * w[12] + d3.y * w[13] + d3.z * w[14] + d3.w * w[15];
    float dtv = softplus_f(sdt);
    float Bn[16] = {b0.x, b0.y, b0.z, b0.w, b1.x, b1.y, b1.z, b1.w,
                    b2.x, b2.y, b2.z, b2.w, b3.x, b3.y, b3.z, b3.w};
    float dtu = dtv * uv;
#pragma unroll
    for (int n = 0; n < 16; ++n) {
      float dA = fast_exp2(dtv * A2[n]);
      ap[n] *= dA;
      h[n] = fmaf(dA, h[n], dtu * Bn[n]);
    }
  }
  const size_t cidx = (((size_t)b * NCH + c) * DI + d) * 16;
  float4* ao = reinterpret_cast<float4*>(APR + cidx);
  float4* ho = reinterpret_cast<float4*>(HLOC + cidx);
#pragma unroll
  for (int q = 0; q < 4; ++q) {
    ao[q] = float4{ap[q * 4], ap[q * 4 + 1], ap[q * 4 + 2], ap[q * 4 + 3]};
    ho[q] = float4{h[q * 4], h[q * 4 + 1], h[q * 4 + 2], h[q * 4 + 3]};
  }
}

// ---------------- scan pass 2: serial carry over chunks ----------------
// thread = b*8192 + d*16 + n; HLOC[c] := carry INTO chunk c (in-place).
__global__ __launch_bounds__(256) void scan_pass2(
    const float* __restrict__ APR, float* __restrict__ HLOC) {
  const int tg = blockIdx.x * 256 + threadIdx.x;  // 0..65535
  const int b = tg >> 13;
  const int rem = tg & 8191;
  const int d = rem >> 4;
  const int n = rem & 15;
  float hin = 0.f;
  for (int c = 0; c < NCH; ++c) {
    const size_t idx = (((size_t)b * NCH + c) * DI + d) * 16 + n;
    float a = APR[idx];
    float hl = HLOC[idx];
    HLOC[idx] = hin;
    hin = fmaf(a, hin, hl);
  }
}

// ---------------- scan pass 3: seeded replay + output (in-place over UC) ---------
__global__ __launch_bounds__(256) void scan_pass3(
    float* __restrict__ UCY, const float* __restrict__ DTR,
    const float* __restrict__ Wdt, const float* __restrict__ bdt,
    const float* __restrict__ Z, const float* __restrict__ BB,
    const float* __restrict__ CB, const float* __restrict__ Alog,
    const float* __restrict__ Dp, const float* __restrict__ HLOC) {
  const int blk = blockIdx.x;
  const int b = blk >> 6;
  const int r = blk & 63;
  const int c = r >> 1;
  const int d = (r & 1) * 256 + threadIdx.x;
  float w[16], A2[16], h[16];
  {
    const float4* w4 = reinterpret_cast<const float4*>(Wdt + (size_t)d * 16);
    const float4* a4 = reinterpret_cast<const float4*>(Alog + (size_t)d * 16);
#pragma unroll
    for (int q = 0; q < 4; ++q) {
      float4 v = w4[q];
      w[q * 4] = v.x; w[q * 4 + 1] = v.y; w[q * 4 + 2] = v.z; w[q * 4 + 3] = v.w;
      float4 a = a4[q];
      A2[q * 4]     = -__expf(a.x) * 1.44269504f;
      A2[q * 4 + 1] = -__expf(a.y) * 1.44269504f;
      A2[q * 4 + 2] = -__expf(a.z) * 1.44269504f;
      A2[q * 4 + 3] = -__expf(a.w) * 1.44269504f;
    }
  }
  const float bias = bdt[d];
  const float Dd = Dp[d];
  {
    const size_t cidx = (((size_t)b * NCH + c) * DI + d) * 16;
    const float4* hs = reinterpret_cast<const float4*>(HLOC + cidx);
#pragma unroll
    for (int q = 0; q < 4; ++q) {
      float4 v = hs[q];
      h[q * 4] = v.x; h[q * 4 + 1] = v.y; h[q * 4 + 2] = v.z; h[q * 4 + 3] = v.w;
    }
  }
  const int t0 = c * CHT;
  for (int tt = 0; tt < CHT; ++tt) {
    const size_t row = (size_t)b * LSEQ + (t0 + tt);
    const float4* dtr4 = reinterpret_cast<const float4*>(DTR + row * 16);
    const float4* bb4 = reinterpret_cast<const float4*>(BB + row * 16);
    const float4* cb4 = reinterpret_cast<const float4*>(CB + row * 16);
    float4 d0 = dtr4[0], d1 = dtr4[1], d2 = dtr4[2], d3 = dtr4[3];
    float4 b0 = bb4[0], b1 = bb4[1], b2 = bb4[2], b3 = bb4[3];
    float4 c0 = cb4[0], c1 = cb4[1], c2 = cb4[2], c3 = cb4[3];
    float uv = UCY[row * DI + d];
    float zv = Z[row * DI + d];
    float sdt = bias
      + d0.x * w[0] + d0.y * w[1] + d0.z * w[2] + d0.w * w[3]
      + d1.x * w[4] + d1.y * w[5] + d1.z * w[6] + d1.w * w[7]
      + d2.x * w[8] + d2.y * w[9] + d2.z * w[10] + d2.w * w[11]
      + d3.x * w[12] + d3.y * w[13] + d3.z * w[14] + d3.w * w[15];
    float dtv = softplus_f(sdt);
    float Bn[16] = {b0.x, b0.y, b0.z, b0.w, b1.x, b1.y, b1.z, b1.w,
                    b2.x, b2.y, b2.z, b2.w, b3.x, b3.y, b3.z, b3.w};
    float Cn[16] = {c0.x, c0.y, c0.z, c0.w, c1.x, c1.y, c1.z, c1.w,
                    c2.x, c2.y, c2.z, c2.w, c3.x, c3.y, c3.z, c3.w};
    float dtu = dtv * uv;
    float y = 0.f;
#pragma unroll
    for (int n = 0; n < 16; ++n) {
      float dA = fast_exp2(dtv * A2[n]);
      h[n] = fmaf(dA, h[n], dtu * Bn[n]);
      y = fmaf(h[n], Cn[n], y);
    }
    UCY[row * DI + d] = (y + Dd * uv) * silu_f(zv);
  }
}

// ---------------- out_proj GEMM: M=16384, N=256, K=512 (+residual, +=) ----------------
__global__ __launch_bounds__(256) void gemm_outproj(
    const float* __restrict__ Y, const float* __restrict__ W,
    const float* __restrict__ X, float* __restrict__ Out, int dir) {
  __shared__ float As[16][132];
  __shared__ float Bs[16][132];
  const int tid = threadIdx.x;
  const int tx = tid & 15, ty = tid >> 4;
  const int bm = blockIdx.y * 128, bn = blockIdx.x * 128;
  const int lr = tid >> 2;
  const int lk = (tid & 3) * 4;
  float acc[8][8] = {};
  for (int k0 = 0; k0 < 512; k0 += 16) {
#pragma unroll
    for (int h = 0; h < 2; ++h) {
      int tl = bm + lr + h * 64;
      float4 v = *reinterpret_cast<const float4*>(Y + (size_t)tl * DI + k0 + lk);
      As[lk + 0][lr + h * 64] = v.x;
      As[lk + 1][lr + h * 64] = v.y;
      As[lk + 2][lr + h * 64] = v.z;
      As[lk + 3][lr + h * 64] = v.w;
    }
#pragma unroll
    for (int h = 0; h < 2; ++h) {
      int wr = bn + lr + h * 64;
      float4 v = *reinterpret_cast<const float4*>(W + (size_t)wr * DI + k0 + lk);
      Bs[lk + 0][lr + h * 64] = v.x;
      Bs[lk + 1][lr + h * 64] = v.y;
      Bs[lk + 2][lr + h * 64] = v.z;
      Bs[lk + 3][lr + h * 64] = v.w;
    }
    __syncthreads();
#pragma unroll
    for (int k = 0; k < 16; ++k) {
      float4 a0 = *reinterpret_cast<const float4*>(&As[k][ty * 8]);
      float4 a1 = *reinterpret_cast<const float4*>(&As[k][ty * 8 + 4]);
      float4 b0 = *reinterpret_cast<const float4*>(&Bs[k][tx * 8]);
      float4 b1 = *reinterpret_cast<const float4*>(&Bs[k][tx * 8 + 4]);
      float a[8] = {a0.x, a0.y, a0.z, a0.w, a1.x, a1.y, a1.z, a1.w};
      float b[8] = {b0.x, b0.y, b0.z, b0.w, b1.x, b1.y, b1.z, b1.w};
#pragma unroll
      for (int i = 0; i < 8; ++i)
#pragma unroll
        for (int j = 0; j < 8; ++j) acc[i][j] = fmaf(a[i], b[j], acc[i][j]);
    }
    __syncthreads();
  }
#pragma unroll
  for (int i = 0; i < 8; ++i) {
    int tl = bm + ty * 8 + i;
    int bidx = tl >> 11, tp = tl & 2047;
    int orow = (bidx << 11) + (dir ? (2047 - tp) : tp);
#pragma unroll
    for (int j = 0; j < 8; j += 4) {
      int col = bn + tx * 8 + j;
      float4 v = {acc[i][j], acc[i][j + 1], acc[i][j + 2], acc[i][j + 3]};
      float4* dst = reinterpret_cast<float4*>(Out + (size_t)orow * DM + col);
      if (dir == 0) {
        float4 r = *reinterpret_cast<const float4*>(X + (size_t)orow * DM + col);
        v.x += r.x; v.y += r.y; v.z += r.z; v.w += r.w;
        *dst = v;
      } else {
        float4 o = *dst;
        o.x += v.x; o.y += v.y; o.z += v.z; o.w += v.w;
        *dst = o;
      }
    }
  }
}

// ---------------- LayerNorm in-place ----------------
__global__ __launch_bounds__(256) void ln_kernel(
    float* __restrict__ H, const float* __restrict__ G, const float* __restrict__ Be) {
  const int lane = threadIdx.x & 63;
  const int row = blockIdx.x * 4 + (threadIdx.x >> 6);
  float4 v = *reinterpret_cast<const float4*>(H + (size_t)row * DM + lane * 4);
  float s = v.x + v.y + v.z + v.w;
  float sq = v.x * v.x + v.y * v.y + v.z * v.z + v.w * v.w;
#pragma unroll
  for (int m = 32; m >= 1; m >>= 1) {
    s += __shfl_xor(s, m);
    sq += __shfl_xor(sq, m);
  }
  float mu = s * (1.f / 256.f);
  float var = sq * (1.f / 256.f) - mu * mu;
  float inv = rsqrtf(var + 1e-5f);
  float4 g = *reinterpret_cast<const float4*>(G + lane * 4);
  float4 be = *reinterpret_cast<const float4*>(Be + lane * 4);
  float4 o;
  o.x = (v.x - mu) * inv * g.x + be.x;
  o.y = (v.y - mu) * inv * g.y + be.y;
  o.z = (v.z - mu) * inv * g.z + be.z;
  o.w = (v.w - mu) * inv * g.w + be.w;
  *reinterpret_cast<float4*>(H + (size_t)row * DM + lane * 4) = o;
}

extern "C" void kernel_launch(void* const* d_in, const int* in_sizes, int n_in,
                              void* d_out, int out_size, void* d_ws, size_t ws_size,
                              hipStream_t stream) {
  const float* x = (const float*)d_in[0];
  const float* ln_g = (const float*)d_in[19];
  const float* ln_b = (const float*)d_in[20];
  float* out = (float*)d_out;
  float* ws = (float*)d_ws;

  float* U = ws;                       // 16384*512 (in_proj u; carries after conv)
  float* Z = U + (size_t)TOK * DI;     // 16384*512
  float* UC = Z + (size_t)TOK * DI;    // 16384*512 (conv out -> Y in-place)
  float* DTR = UC + (size_t)TOK * DI;  // 16384*16
  float* BB = DTR + (size_t)TOK * 16;  // 16384*16
  float* CB = BB + (size_t)TOK * 16;   // 16384*16
  // Carries alias U (u is dead after conv): 8*32*512*16 floats each = 8.4 MB.
  float* APR = U;
  float* HLOC = U + (size_t)8 * NCH * DI * NST;

  for (int dir = 0; dir < 2; ++dir) {
    const float* Win = (const float*)d_in[1 + dir * 9];
    const float* cw = (const float*)d_in[2 + dir * 9];
    const float* cb = (const float*)d_in[3 + dir * 9];
    const float* Wx = (const float*)d_in[4 + dir * 9];
    const float* Wdt = (const float*)d_in[5 + dir * 9];
    const float* bdt = (const float*)d_in[6 + dir * 9];
    const float* Alog = (const float*)d_in[7 + dir * 9];
    const float* Dp = (const float*)d_in[8 + dir * 9];
    const float* Wout = (const float*)d_in[9 + dir * 9];

    gemm_inproj<<<dim3(8, 128), 256, 0, stream>>>(x, Win, U, Z, dir);
    conv_kernel<<<(TOK * DI) / 256, 256, 0, stream>>>(U, cw, cb, UC);
    gemm_xproj<<<TOK / 64, 256, 0, stream>>>(UC, Wx, DTR, BB, CB);
    scan_pass1<<<512, 256, 0, stream>>>(UC, DTR, Wdt, bdt, BB, Alog, APR, HLOC);
    scan_pass2<<<256, 256, 0, stream>>>(APR, HLOC);
    scan_pass3<<<512, 256, 0, stream>>>(UC, DTR, Wdt, bdt, Z, BB, CB, Alog, Dp, HLOC);
    gemm_outproj<<<dim3(2, 128), 256, 0, stream>>>(UC, Wout, x, out, dir);
  }
  ln_kernel<<<TOK / 4, 256, 0, stream>>>(out, ln_g, ln_b);
}

// Round 10
// 674.044 us; speedup vs baseline: 6.7085x; 1.2607x over previous
//
#include <hip/hip_runtime.h>
#include <hip/hip_bf16.h>
#include <math.h>

// BiMambaBlock: B=8, L=2048, D_MODEL=256, D_INNER=512, N=16, DT_RANK=16, D_CONV=4
// Chunked 3-pass scan (proven, r9: 850us) + bf16-MFMA in_proj/out_proj (this round).
//
// Per direction:
//  0) cvt: x -> XB (bf16, once), Win -> WinB, Wout -> WoutB (bf16, per dir)
//  1) in_proj MFMA GEMM (bf16 in, fp32 out): U, Z
//  2) conv4 + silu (fp32): U -> UC
//  3) x_proj GEMM (fp32): UC -> DTR|BB|CB
//  4-6) 3-pass chunked scan; pass3 writes Y as bf16 -> YB
//  7) out_proj MFMA GEMM: out[flip] (+)= YB @ WoutB^T (+x residual on dir0)
// Then LayerNorm in-place.
// MFMA frag layouts (16x16x32 bf16, m89-verified): A row=lane&15,k=(lane>>4)*8+i;
// B col=lane&15 same k; C/D col=lane&15,row=(lane>>4)*4+reg. Both A,B load as
// 16B contiguous from row-major [M][K]/[N][K] bf16 -> no LDS, no transpose.

#define TOK 16384
#define LSEQ 2048
#define DI 512
#define DM 256
#define NST 16
#define NCH 32
#define CHT 64

typedef __attribute__((ext_vector_type(8))) short bf16x8;
typedef __attribute__((ext_vector_type(4))) float f32x4;

__device__ __forceinline__ float fast_exp2(float x) {
#if defined(__has_builtin)
#if __has_builtin(__builtin_amdgcn_exp2f)
  return __builtin_amdgcn_exp2f(x);
#else
  return exp2f(x);
#endif
#else
  return exp2f(x);
#endif
}

__device__ __forceinline__ float silu_f(float v) {
  return v / (1.f + __expf(-v));
}

__device__ __forceinline__ float softplus_f(float s) {
  return (s > 20.f) ? s : log1pf(__expf(s));
}

// ---------------- fp32 -> bf16 conversion (vectorized x4) ----------------
__global__ __launch_bounds__(256) void cvt_f32_bf16(
    const float* __restrict__ in, ushort* __restrict__ out, int n4) {
  int i = blockIdx.x * 256 + threadIdx.x;
  if (i >= n4) return;
  float4 v = *reinterpret_cast<const float4*>(in + (size_t)i * 4);
  __hip_bfloat16 b0 = __float2bfloat16(v.x);
  __hip_bfloat16 b1 = __float2bfloat16(v.y);
  __hip_bfloat16 b2 = __float2bfloat16(v.z);
  __hip_bfloat16 b3 = __float2bfloat16(v.w);
  ushort4 o = {*reinterpret_cast<ushort*>(&b0), *reinterpret_cast<ushort*>(&b1),
               *reinterpret_cast<ushort*>(&b2), *reinterpret_cast<ushort*>(&b3)};
  *reinterpret_cast<ushort4*>(out + (size_t)i * 4) = o;
}

// ---------------- in_proj MFMA: M=16384, N=1024, K=256 ----------------
// block 128x128 (4 waves 2x2, 64x64/wave); A=XB (flip rows), B=WinB.
__global__ __launch_bounds__(256) void gemm_inproj_mfma(
    const ushort* __restrict__ XB, const ushort* __restrict__ WB,
    float* __restrict__ U, float* __restrict__ Z, int dir) {
  const int tid = threadIdx.x;
  const int wid = tid >> 6, lane = tid & 63;
  const int wm = wid >> 1, wn = wid & 1;
  const int bm = blockIdx.y * 128, bn = blockIdx.x * 128;
  const int lrow = lane & 15, kg = lane >> 4;
  f32x4 acc[4][4] = {};
  const ushort* aptr[4];
  const ushort* bptr[4];
#pragma unroll
  for (int mt = 0; mt < 4; ++mt) {
    int row = bm + wm * 64 + mt * 16 + lrow;
    int bb = row >> 11, tp = row & 2047;
    int src = (bb << 11) + (dir ? (2047 - tp) : tp);
    aptr[mt] = XB + (size_t)src * 256 + kg * 8;
  }
#pragma unroll
  for (int nt = 0; nt < 4; ++nt) {
    int col = bn + wn * 64 + nt * 16 + lrow;
    bptr[nt] = WB + (size_t)col * 256 + kg * 8;
  }
  for (int k0 = 0; k0 < 256; k0 += 32) {
    bf16x8 a[4], b[4];
#pragma unroll
    for (int mt = 0; mt < 4; ++mt)
      a[mt] = *reinterpret_cast<const bf16x8*>(aptr[mt] + k0);
#pragma unroll
    for (int nt = 0; nt < 4; ++nt)
      b[nt] = *reinterpret_cast<const bf16x8*>(bptr[nt] + k0);
#pragma unroll
    for (int mt = 0; mt < 4; ++mt)
#pragma unroll
      for (int nt = 0; nt < 4; ++nt)
        acc[mt][nt] = __builtin_amdgcn_mfma_f32_16x16x32_bf16(a[mt], b[nt], acc[mt][nt], 0, 0, 0);
  }
#pragma unroll
  for (int mt = 0; mt < 4; ++mt) {
#pragma unroll
    for (int r = 0; r < 4; ++r) {
      int row = bm + wm * 64 + mt * 16 + kg * 4 + r;
#pragma unroll
      for (int nt = 0; nt < 4; ++nt) {
        int col = bn + wn * 64 + nt * 16 + lrow;
        float v = acc[mt][nt][r];
        if (col < DI) U[(size_t)row * DI + col] = v;
        else Z[(size_t)row * DI + (col - DI)] = v;
      }
    }
  }
}

// ---------------- out_proj MFMA: M=16384, N=256, K=512 ----------------
// block 128x64 (4 waves 2x2, 64x32/wave); A=YB, B=WoutB; flip+residual on store.
__global__ __launch_bounds__(256) void gemm_outproj_mfma(
    const ushort* __restrict__ YB, const ushort* __restrict__ WB,
    const float* __restrict__ X, float* __restrict__ Out, int dir) {
  const int tid = threadIdx.x;
  const int wid = tid >> 6, lane = tid & 63;
  const int wm = wid >> 1, wn = wid & 1;
  const int bm = blockIdx.y * 128, bn = blockIdx.x * 64;
  const int lrow = lane & 15, kg = lane >> 4;
  f32x4 acc[4][2] = {};
  const ushort* aptr[4];
  const ushort* bptr[2];
#pragma unroll
  for (int mt = 0; mt < 4; ++mt) {
    int row = bm + wm * 64 + mt * 16 + lrow;
    aptr[mt] = YB + (size_t)row * DI + kg * 8;
  }
#pragma unroll
  for (int nt = 0; nt < 2; ++nt) {
    int col = bn + wn * 32 + nt * 16 + lrow;
    bptr[nt] = WB + (size_t)col * DI + kg * 8;
  }
  for (int k0 = 0; k0 < 512; k0 += 32) {
    bf16x8 a[4], b[2];
#pragma unroll
    for (int mt = 0; mt < 4; ++mt)
      a[mt] = *reinterpret_cast<const bf16x8*>(aptr[mt] + k0);
#pragma unroll
    for (int nt = 0; nt < 2; ++nt)
      b[nt] = *reinterpret_cast<const bf16x8*>(bptr[nt] + k0);
#pragma unroll
    for (int mt = 0; mt < 4; ++mt)
#pragma unroll
      for (int nt = 0; nt < 2; ++nt)
        acc[mt][nt] = __builtin_amdgcn_mfma_f32_16x16x32_bf16(a[mt], b[nt], acc[mt][nt], 0, 0, 0);
  }
#pragma unroll
  for (int mt = 0; mt < 4; ++mt) {
#pragma unroll
    for (int r = 0; r < 4; ++r) {
      int row = bm + wm * 64 + mt * 16 + kg * 4 + r;
      int bb = row >> 11, tp = row & 2047;
      int orow = (bb << 11) + (dir ? (2047 - tp) : tp);
#pragma unroll
      for (int nt = 0; nt < 2; ++nt) {
        int col = bn + wn * 32 + nt * 16 + lrow;
        float v = acc[mt][nt][r];
        size_t oi = (size_t)orow * DM + col;
        if (dir == 0) Out[oi] = v + X[oi];
        else Out[oi] += v;
      }
    }
  }
}

// ---------------- causal depthwise conv4 + bias + silu ----------------
__global__ __launch_bounds__(256) void conv_kernel(
    const float* __restrict__ U, const float* __restrict__ CW,
    const float* __restrict__ CB, float* __restrict__ UC) {
  int idx = blockIdx.x * 256 + threadIdx.x;
  int tl = idx >> 9, d = idx & 511;
  int tp = tl & 2047;
  float4 w4 = *reinterpret_cast<const float4*>(CW + (size_t)d * 4);
  float u3 = U[idx];
  float u2 = (tp >= 1) ? U[idx - 512] : 0.f;
  float u1 = (tp >= 2) ? U[idx - 1024] : 0.f;
  float u0 = (tp >= 3) ? U[idx - 1536] : 0.f;
  float acc = CB[d] + w4.x * u0 + w4.y * u1 + w4.z * u2 + w4.w * u3;
  UC[idx] = silu_f(acc);
}

// ---------------- x_proj GEMM: M=16384, N=48, K=512 (fp32) ----------------
__global__ __launch_bounds__(256) void gemm_xproj(
    const float* __restrict__ UC, const float* __restrict__ W,
    float* __restrict__ DTR, float* __restrict__ BB, float* __restrict__ CB) {
  __shared__ float As[32][68];
  __shared__ float Ws[32][52];
  const int tid = threadIdx.x;
  const int bm = blockIdx.x * 64;
  const int tx = tid & 15, ty = tid >> 4;
  float acc[4][3] = {};
  for (int k0 = 0; k0 < 512; k0 += 32) {
#pragma unroll
    for (int h = 0; h < 2; ++h) {
      int f = tid + h * 256;
      int r = f >> 3, kk = (f & 7) * 4;
      float4 v = *reinterpret_cast<const float4*>(UC + (size_t)(bm + r) * DI + k0 + kk);
      As[kk + 0][r] = v.x;
      As[kk + 1][r] = v.y;
      As[kk + 2][r] = v.z;
      As[kk + 3][r] = v.w;
    }
    {
      int f = tid;
      int r = f >> 3, kk = (f & 7) * 4;
      float4 v = *reinterpret_cast<const float4*>(W + (size_t)r * DI + k0 + kk);
      Ws[kk + 0][r] = v.x;
      Ws[kk + 1][r] = v.y;
      Ws[kk + 2][r] = v.z;
      Ws[kk + 3][r] = v.w;
    }
    if (tid < 128) {
      int f = tid + 256;
      int r = f >> 3, kk = (f & 7) * 4;
      float4 v = *reinterpret_cast<const float4*>(W + (size_t)r * DI + k0 + kk);
      Ws[kk + 0][r] = v.x;
      Ws[kk + 1][r] = v.y;
      Ws[kk + 2][r] = v.z;
      Ws[kk + 3][r] = v.w;
    }
    __syncthreads();
#pragma unroll
    for (int k = 0; k < 32; ++k) {
      float a[4], w[3];
#pragma unroll
      for (int i = 0; i < 4; ++i) a[i] = As[k][ty * 4 + i];
#pragma unroll
      for (int j = 0; j < 3; ++j) w[j] = Ws[k][tx * 3 + j];
#pragma unroll
      for (int i = 0; i < 4; ++i)
#pragma unroll
        for (int j = 0; j < 3; ++j) acc[i][j] = fmaf(a[i], w[j], acc[i][j]);
    }
    __syncthreads();
  }
#pragma unroll
  for (int i = 0; i < 4; ++i) {
    int row = bm + ty * 4 + i;
#pragma unroll
    for (int j = 0; j < 3; ++j) {
      int c = tx * 3 + j;
      float* dst = (c < 16) ? DTR : (c < 32) ? BB : CB;
      dst[(size_t)row * 16 + (c & 15)] = acc[i][j];
    }
  }
}

// ---------------- scan pass 1: per-chunk local scan + dA product ----------------
__global__ __launch_bounds__(256) void scan_pass1(
    const float* __restrict__ UC, const float* __restrict__ DTR,
    const float* __restrict__ Wdt, const float* __restrict__ bdt,
    const float* __restrict__ BB, const float* __restrict__ Alog,
    float* __restrict__ APR, float* __restrict__ HLOC) {
  const int blk = blockIdx.x;
  const int b = blk >> 6;
  const int r = blk & 63;
  const int c = r >> 1;
  const int d = (r & 1) * 256 + threadIdx.x;
  float w[16], A2[16], h[16], ap[16];
  {
    const float4* w4 = reinterpret_cast<const float4*>(Wdt + (size_t)d * 16);
    const float4* a4 = reinterpret_cast<const float4*>(Alog + (size_t)d * 16);
#pragma unroll
    for (int q = 0; q < 4; ++q) {
      float4 v = w4[q];
      w[q * 4] = v.x; w[q * 4 + 1] = v.y; w[q * 4 + 2] = v.z; w[q * 4 + 3] = v.w;
      float4 a = a4[q];
      A2[q * 4]     = -__expf(a.x) * 1.44269504f;
      A2[q * 4 + 1] = -__expf(a.y) * 1.44269504f;
      A2[q * 4 + 2] = -__expf(a.z) * 1.44269504f;
      A2[q * 4 + 3] = -__expf(a.w) * 1.44269504f;
    }
  }
  const float bias = bdt[d];
#pragma unroll
  for (int n = 0; n < 16; ++n) { h[n] = 0.f; ap[n] = 1.f; }
  const int t0 = c * CHT;
  for (int tt = 0; tt < CHT; ++tt) {
    const size_t row = (size_t)b * LSEQ + (t0 + tt);
    const float4* dtr4 = reinterpret_cast<const float4*>(DTR + row * 16);
    const float4* bb4 = reinterpret_cast<const float4*>(BB + row * 16);
    float4 d0 = dtr4[0], d1 = dtr4[1], d2 = dtr4[2], d3 = dtr4[3];
    float4 b0 = bb4[0], b1 = bb4[1], b2 = bb4[2], b3 = bb4[3];
    float uv = UC[row * DI + d];
    float sdt = bias
      + d0.x * w[0] + d0.y * w[1] + d0.z * w[2] + d0.w * w[3]
      + d1.x * w[4] + d1.y * w[5] + d1.z * w[6] + d1.w * w[7]
      + d2.x * w[8] + d2.y * w[9] + d2.z * w[10] + d2.w * w[11]
      + d3.x * w[12] + d3.y * w[13] + d3.z * w[14] + d3.w * w[15];
    float dtv = softplus_f(sdt);
    float Bn[16] = {b0.x, b0.y, b0.z, b0.w, b1.x, b1.y, b1.z, b1.w,
                    b2.x, b2.y, b2.z, b2.w, b3.x, b3.y, b3.z, b3.w};
    float dtu = dtv * uv;
#pragma unroll
    for (int n = 0; n < 16; ++n) {
      float dA = fast_exp2(dtv * A2[n]);
      ap[n] *= dA;
      h[n] = fmaf(dA, h[n], dtu * Bn[n]);
    }
  }
  const size_t cidx = (((size_t)b * NCH + c) * DI + d) * 16;
  float4* ao = reinterpret_cast<float4*>(APR + cidx);
  float4* ho = reinterpret_cast<float4*>(HLOC + cidx);
#pragma unroll
  for (int q = 0; q < 4; ++q) {
    ao[q] = float4{ap[q * 4], ap[q * 4 + 1], ap[q * 4 + 2], ap[q * 4 + 3]};
    ho[q] = float4{h[q * 4], h[q * 4 + 1], h[q * 4 + 2], h[q * 4 + 3]};
  }
}

// ---------------- scan pass 2: serial carry over chunks ----------------
__global__ __launch_bounds__(256) void scan_pass2(
    const float* __restrict__ APR, float* __restrict__ HLOC) {
  const int tg = blockIdx.x * 256 + threadIdx.x;
  const int b = tg >> 13;
  const int rem = tg & 8191;
  const int d = rem >> 4;
  const int n = rem & 15;
  float hin = 0.f;
  for (int c = 0; c < NCH; ++c) {
    const size_t idx = (((size_t)b * NCH + c) * DI + d) * 16 + n;
    float a = APR[idx];
    float hl = HLOC[idx];
    HLOC[idx] = hin;
    hin = fmaf(a, hin, hl);
  }
}

// ---------------- scan pass 3: seeded replay; Y written as bf16 -> YB ----------
__global__ __launch_bounds__(256) void scan_pass3(
    const float* __restrict__ UC, const float* __restrict__ DTR,
    const float* __restrict__ Wdt, const float* __restrict__ bdt,
    const float* __restrict__ Z, const float* __restrict__ BB,
    const float* __restrict__ CB, const float* __restrict__ Alog,
    const float* __restrict__ Dp, const float* __restrict__ HLOC,
    ushort* __restrict__ YB) {
  const int blk = blockIdx.x;
  const int b = blk >> 6;
  const int r = blk & 63;
  const int c = r >> 1;
  const int d = (r & 1) * 256 + threadIdx.x;
  float w[16], A2[16], h[16];
  {
    const float4* w4 = reinterpret_cast<const float4*>(Wdt + (size_t)d * 16);
    const float4* a4 = reinterpret_cast<const float4*>(Alog + (size_t)d * 16);
#pragma unroll
    for (int q = 0; q < 4; ++q) {
      float4 v = w4[q];
      w[q * 4] = v.x; w[q * 4 + 1] = v.y; w[q * 4 + 2] = v.z; w[q * 4 + 3] = v.w;
      float4 a = a4[q];
      A2[q * 4]     = -__expf(a.x) * 1.44269504f;
      A2[q * 4 + 1] = -__expf(a.y) * 1.44269504f;
      A2[q * 4 + 2] = -__expf(a.z) * 1.44269504f;
      A2[q * 4 + 3] = -__expf(a.w) * 1.44269504f;
    }
  }
  const float bias = bdt[d];
  const float Dd = Dp[d];
  {
    const size_t cidx = (((size_t)b * NCH + c) * DI + d) * 16;
    const float4* hs = reinterpret_cast<const float4*>(HLOC + cidx);
#pragma unroll
    for (int q = 0; q < 4; ++q) {
      float4 v = hs[q];
      h[q * 4] = v.x; h[q * 4 + 1] = v.y; h[q * 4 + 2] = v.z; h[q * 4 + 3] = v.w;
    }
  }
  const int t0 = c * CHT;
  for (int tt = 0; tt < CHT; ++tt) {
    const size_t row = (size_t)b * LSEQ + (t0 + tt);
    const float4* dtr4 = reinterpret_cast<const float4*>(DTR + row * 16);
    const float4* bb4 = reinterpret_cast<const float4*>(BB + row * 16);
    const float4* cb4 = reinterpret_cast<const float4*>(CB + row * 16);
    float4 d0 = dtr4[0], d1 = dtr4[1], d2 = dtr4[2], d3 = dtr4[3];
    float4 b0 = bb4[0], b1 = bb4[1], b2 = bb4[2], b3 = bb4[3];
    float4 c0 = cb4[0], c1 = cb4[1], c2 = cb4[2], c3 = cb4[3];
    float uv = UC[row * DI + d];
    float zv = Z[row * DI + d];
    float sdt = bias
      + d0.x * w[0] + d0.y * w[1] + d0.z * w[2] + d0.w * w[3]
      + d1.x * w[4] + d1.y * w[5] + d1.z * w[6] + d1.w * w[7]
      + d2.x * w[8] + d2.y * w[9] + d2.z * w[10] + d2.w * w[11]
      + d3.x * w[12] + d3.y * w[13] + d3.z * w[14] + d3.w * w[15];
    float dtv = softplus_f(sdt);
    float Bn[16] = {b0.x, b0.y, b0.z, b0.w, b1.x, b1.y, b1.z, b1.w,
                    b2.x, b2.y, b2.z, b2.w, b3.x, b3.y, b3.z, b3.w};
    float Cn[16] = {c0.x, c0.y, c0.z, c0.w, c1.x, c1.y, c1.z, c1.w,
                    c2.x, c2.y, c2.z, c2.w, c3.x, c3.y, c3.z, c3.w};
    float dtu = dtv * uv;
    float y = 0.f;
#pragma unroll
    for (int n = 0; n < 16; ++n) {
      float dA = fast_exp2(dtv * A2[n]);
      h[n] = fmaf(dA, h[n], dtu * Bn[n]);
      y = fmaf(h[n], Cn[n], y);
    }
    float yo = (y + Dd * uv) * silu_f(zv);
    __hip_bfloat16 hb = __float2bfloat16(yo);
    YB[row * DI + d] = *reinterpret_cast<ushort*>(&hb);
  }
}

// ---------------- LayerNorm in-place ----------------
__global__ __launch_bounds__(256) void ln_kernel(
    float* __restrict__ H, const float* __restrict__ G, const float* __restrict__ Be) {
  const int lane = threadIdx.x & 63;
  const int row = blockIdx.x * 4 + (threadIdx.x >> 6);
  float4 v = *reinterpret_cast<const float4*>(H + (size_t)row * DM + lane * 4);
  float s = v.x + v.y + v.z + v.w;
  float sq = v.x * v.x + v.y * v.y + v.z * v.z + v.w * v.w;
#pragma unroll
  for (int m = 32; m >= 1; m >>= 1) {
    s += __shfl_xor(s, m);
    sq += __shfl_xor(sq, m);
  }
  float mu = s * (1.f / 256.f);
  float var = sq * (1.f / 256.f) - mu * mu;
  float inv = rsqrtf(var + 1e-5f);
  float4 g = *reinterpret_cast<const float4*>(G + lane * 4);
  float4 be = *reinterpret_cast<const float4*>(Be + lane * 4);
  float4 o;
  o.x = (v.x - mu) * inv * g.x + be.x;
  o.y = (v.y - mu) * inv * g.y + be.y;
  o.z = (v.z - mu) * inv * g.z + be.z;
  o.w = (v.w - mu) * inv * g.w + be.w;
  *reinterpret_cast<float4*>(H + (size_t)row * DM + lane * 4) = o;
}

extern "C" void kernel_launch(void* const* d_in, const int* in_sizes, int n_in,
                              void* d_out, int out_size, void* d_ws, size_t ws_size,
                              hipStream_t stream) {
  const float* x = (const float*)d_in[0];
  const float* ln_g = (const float*)d_in[19];
  const float* ln_b = (const float*)d_in[20];
  float* out = (float*)d_out;
  float* ws = (float*)d_ws;

  float* U = ws;                        // TOK*DI fp32 (u; APR/HLOC alias after conv)
  float* Z = U + (size_t)TOK * DI;      // TOK*DI fp32
  float* UC = Z + (size_t)TOK * DI;     // TOK*DI fp32
  float* DTR = UC + (size_t)TOK * DI;   // TOK*16
  float* BB = DTR + (size_t)TOK * 16;
  float* CB = BB + (size_t)TOK * 16;
  float* fend = CB + (size_t)TOK * 16;
  ushort* XB = (ushort*)fend;                     // TOK*256 bf16 (8.4 MB)
  ushort* YB = XB + (size_t)TOK * 256;            // TOK*DI bf16 (16.8 MB)
  ushort* WinB = YB + (size_t)TOK * DI;           // 1024*256 bf16
  ushort* WoutB = WinB + (size_t)1024 * 256;      // 256*512 bf16
  float* APR = U;                                 // alias (u dead after conv)
  float* HLOC = U + (size_t)8 * NCH * DI * NST;

  cvt_f32_bf16<<<(TOK * 256 / 4 + 255) / 256, 256, 0, stream>>>(x, XB, TOK * 256 / 4);

  for (int dir = 0; dir < 2; ++dir) {
    const float* Win = (const float*)d_in[1 + dir * 9];
    const float* cw = (const float*)d_in[2 + dir * 9];
    const float* cb = (const float*)d_in[3 + dir * 9];
    const float* Wx = (const float*)d_in[4 + dir * 9];
    const float* Wdt = (const float*)d_in[5 + dir * 9];
    const float* bdt = (const float*)d_in[6 + dir * 9];
    const float* Alog = (const float*)d_in[7 + dir * 9];
    const float* Dp = (const float*)d_in[8 + dir * 9];
    const float* Wout = (const float*)d_in[9 + dir * 9];

    cvt_f32_bf16<<<256, 256, 0, stream>>>(Win, WinB, 1024 * 256 / 4);
    cvt_f32_bf16<<<128, 256, 0, stream>>>(Wout, WoutB, 256 * 512 / 4);
    gemm_inproj_mfma<<<dim3(8, 128), 256, 0, stream>>>(XB, WinB, U, Z, dir);
    conv_kernel<<<(TOK * DI) / 256, 256, 0, stream>>>(U, cw, cb, UC);
    gemm_xproj<<<TOK / 64, 256, 0, stream>>>(UC, Wx, DTR, BB, CB);
    scan_pass1<<<512, 256, 0, stream>>>(UC, DTR, Wdt, bdt, BB, Alog, APR, HLOC);
    scan_pass2<<<256, 256, 0, stream>>>(APR, HLOC);
    scan_pass3<<<512, 256, 0, stream>>>(UC, DTR, Wdt, bdt, Z, BB, CB, Alog, Dp, HLOC, YB);
    gemm_outproj_mfma<<<dim3(4, 128), 256, 0, stream>>>(YB, WoutB, x, out, dir);
  }
  ln_kernel<<<TOK / 4, 256, 0, stream>>>(out, ln_g, ln_b);
}

// Round 14
// 653.075 us; speedup vs baseline: 6.9239x; 1.0321x over previous
//
#include <hip/hip_runtime.h>
#include <hip/hip_bf16.h>
#include <math.h>

// BiMambaBlock: B=8, L=2048, D_MODEL=256, D_INNER=512, N=16, DT_RANK=16, D_CONV=4
// r9: chunked 3-pass scan (850us). r10: bf16-MFMA in/out_proj (674us).
// r11 (this): scan latency fix -- NCH 32->64 (4 blocks/CU) + unroll 2 on t-loops.
//
// Per direction:
//  0) cvt: x -> XB (bf16, once), Win -> WinB, Wout -> WoutB (bf16, per dir)
//  1) in_proj MFMA GEMM (bf16 in, fp32 out): U, Z
//  2) conv4 + silu (fp32): U -> UC
//  3) x_proj GEMM (fp32): UC -> DTR|BB|CB
//  4-6) 3-pass chunked scan (64 chunks x 32 steps); pass3 writes Y bf16 -> YB
//  7) out_proj MFMA GEMM: out[flip] (+)= YB @ WoutB^T (+x residual on dir0)
// Then LayerNorm in-place.
// APR/HLOC alias U (dead after conv): 2 x 16.77 MB = 33.55 MB = U exactly.

#define TOK 16384
#define LSEQ 2048
#define DI 512
#define DM 256
#define NST 16
#define NCH 64
#define CHT 32

typedef __attribute__((ext_vector_type(8))) short bf16x8;
typedef __attribute__((ext_vector_type(4))) float f32x4;

__device__ __forceinline__ float fast_exp2(float x) {
#if defined(__has_builtin)
#if __has_builtin(__builtin_amdgcn_exp2f)
  return __builtin_amdgcn_exp2f(x);
#else
  return exp2f(x);
#endif
#else
  return exp2f(x);
#endif
}

__device__ __forceinline__ float silu_f(float v) {
  return v / (1.f + __expf(-v));
}

__device__ __forceinline__ float softplus_f(float s) {
  return (s > 20.f) ? s : log1pf(__expf(s));
}

// ---------------- fp32 -> bf16 conversion (vectorized x4) ----------------
__global__ __launch_bounds__(256) void cvt_f32_bf16(
    const float* __restrict__ in, ushort* __restrict__ out, int n4) {
  int i = blockIdx.x * 256 + threadIdx.x;
  if (i >= n4) return;
  float4 v = *reinterpret_cast<const float4*>(in + (size_t)i * 4);
  __hip_bfloat16 b0 = __float2bfloat16(v.x);
  __hip_bfloat16 b1 = __float2bfloat16(v.y);
  __hip_bfloat16 b2 = __float2bfloat16(v.z);
  __hip_bfloat16 b3 = __float2bfloat16(v.w);
  ushort4 o = {*reinterpret_cast<ushort*>(&b0), *reinterpret_cast<ushort*>(&b1),
               *reinterpret_cast<ushort*>(&b2), *reinterpret_cast<ushort*>(&b3)};
  *reinterpret_cast<ushort4*>(out + (size_t)i * 4) = o;
}

// ---------------- in_proj MFMA: M=16384, N=1024, K=256 ----------------
__global__ __launch_bounds__(256) void gemm_inproj_mfma(
    const ushort* __restrict__ XB, const ushort* __restrict__ WB,
    float* __restrict__ U, float* __restrict__ Z, int dir) {
  const int tid = threadIdx.x;
  const int wid = tid >> 6, lane = tid & 63;
  const int wm = wid >> 1, wn = wid & 1;
  const int bm = blockIdx.y * 128, bn = blockIdx.x * 128;
  const int lrow = lane & 15, kg = lane >> 4;
  f32x4 acc[4][4] = {};
  const ushort* aptr[4];
  const ushort* bptr[4];
#pragma unroll
  for (int mt = 0; mt < 4; ++mt) {
    int row = bm + wm * 64 + mt * 16 + lrow;
    int bb = row >> 11, tp = row & 2047;
    int src = (bb << 11) + (dir ? (2047 - tp) : tp);
    aptr[mt] = XB + (size_t)src * 256 + kg * 8;
  }
#pragma unroll
  for (int nt = 0; nt < 4; ++nt) {
    int col = bn + wn * 64 + nt * 16 + lrow;
    bptr[nt] = WB + (size_t)col * 256 + kg * 8;
  }
  for (int k0 = 0; k0 < 256; k0 += 32) {
    bf16x8 a[4], b[4];
#pragma unroll
    for (int mt = 0; mt < 4; ++mt)
      a[mt] = *reinterpret_cast<const bf16x8*>(aptr[mt] + k0);
#pragma unroll
    for (int nt = 0; nt < 4; ++nt)
      b[nt] = *reinterpret_cast<const bf16x8*>(bptr[nt] + k0);
#pragma unroll
    for (int mt = 0; mt < 4; ++mt)
#pragma unroll
      for (int nt = 0; nt < 4; ++nt)
        acc[mt][nt] = __builtin_amdgcn_mfma_f32_16x16x32_bf16(a[mt], b[nt], acc[mt][nt], 0, 0, 0);
  }
#pragma unroll
  for (int mt = 0; mt < 4; ++mt) {
#pragma unroll
    for (int r = 0; r < 4; ++r) {
      int row = bm + wm * 64 + mt * 16 + kg * 4 + r;
#pragma unroll
      for (int nt = 0; nt < 4; ++nt) {
        int col = bn + wn * 64 + nt * 16 + lrow;
        float v = acc[mt][nt][r];
        if (col < DI) U[(size_t)row * DI + col] = v;
        else Z[(size_t)row * DI + (col - DI)] = v;
      }
    }
  }
}

// ---------------- out_proj MFMA: M=16384, N=256, K=512 ----------------
__global__ __launch_bounds__(256) void gemm_outproj_mfma(
    const ushort* __restrict__ YB, const ushort* __restrict__ WB,
    const float* __restrict__ X, float* __restrict__ Out, int dir) {
  const int tid = threadIdx.x;
  const int wid = tid >> 6, lane = tid & 63;
  const int wm = wid >> 1, wn = wid & 1;
  const int bm = blockIdx.y * 128, bn = blockIdx.x * 64;
  const int lrow = lane & 15, kg = lane >> 4;
  f32x4 acc[4][2] = {};
  const ushort* aptr[4];
  const ushort* bptr[2];
#pragma unroll
  for (int mt = 0; mt < 4; ++mt) {
    int row = bm + wm * 64 + mt * 16 + lrow;
    aptr[mt] = YB + (size_t)row * DI + kg * 8;
  }
#pragma unroll
  for (int nt = 0; nt < 2; ++nt) {
    int col = bn + wn * 32 + nt * 16 + lrow;
    bptr[nt] = WB + (size_t)col * DI + kg * 8;
  }
  for (int k0 = 0; k0 < 512; k0 += 32) {
    bf16x8 a[4], b[2];
#pragma unroll
    for (int mt = 0; mt < 4; ++mt)
      a[mt] = *reinterpret_cast<const bf16x8*>(aptr[mt] + k0);
#pragma unroll
    for (int nt = 0; nt < 2; ++nt)
      b[nt] = *reinterpret_cast<const bf16x8*>(bptr[nt] + k0);
#pragma unroll
    for (int mt = 0; mt < 4; ++mt)
#pragma unroll
      for (int nt = 0; nt < 2; ++nt)
        acc[mt][nt] = __builtin_amdgcn_mfma_f32_16x16x32_bf16(a[mt], b[nt], acc[mt][nt], 0, 0, 0);
  }
#pragma unroll
  for (int mt = 0; mt < 4; ++mt) {
#pragma unroll
    for (int r = 0; r < 4; ++r) {
      int row = bm + wm * 64 + mt * 16 + kg * 4 + r;
      int bb = row >> 11, tp = row & 2047;
      int orow = (bb << 11) + (dir ? (2047 - tp) : tp);
#pragma unroll
      for (int nt = 0; nt < 2; ++nt) {
        int col = bn + wn * 32 + nt * 16 + lrow;
        float v = acc[mt][nt][r];
        size_t oi = (size_t)orow * DM + col;
        if (dir == 0) Out[oi] = v + X[oi];
        else Out[oi] += v;
      }
    }
  }
}

// ---------------- causal depthwise conv4 + bias + silu ----------------
__global__ __launch_bounds__(256) void conv_kernel(
    const float* __restrict__ U, const float* __restrict__ CW,
    const float* __restrict__ CB, float* __restrict__ UC) {
  int idx = blockIdx.x * 256 + threadIdx.x;
  int tl = idx >> 9, d = idx & 511;
  int tp = tl & 2047;
  float4 w4 = *reinterpret_cast<const float4*>(CW + (size_t)d * 4);
  float u3 = U[idx];
  float u2 = (tp >= 1) ? U[idx - 512] : 0.f;
  float u1 = (tp >= 2) ? U[idx - 1024] : 0.f;
  float u0 = (tp >= 3) ? U[idx - 1536] : 0.f;
  float acc = CB[d] + w4.x * u0 + w4.y * u1 + w4.z * u2 + w4.w * u3;
  UC[idx] = silu_f(acc);
}

// ---------------- x_proj GEMM: M=16384, N=48, K=512 (fp32) ----------------
__global__ __launch_bounds__(256) void gemm_xproj(
    const float* __restrict__ UC, const float* __restrict__ W,
    float* __restrict__ DTR, float* __restrict__ BB, float* __restrict__ CB) {
  __shared__ float As[32][68];
  __shared__ float Ws[32][52];
  const int tid = threadIdx.x;
  const int bm = blockIdx.x * 64;
  const int tx = tid & 15, ty = tid >> 4;
  float acc[4][3] = {};
  for (int k0 = 0; k0 < 512; k0 += 32) {
#pragma unroll
    for (int h = 0; h < 2; ++h) {
      int f = tid + h * 256;
      int r = f >> 3, kk = (f & 7) * 4;
      float4 v = *reinterpret_cast<const float4*>(UC + (size_t)(bm + r) * DI + k0 + kk);
      As[kk + 0][r] = v.x;
      As[kk + 1][r] = v.y;
      As[kk + 2][r] = v.z;
      As[kk + 3][r] = v.w;
    }
    {
      int f = tid;
      int r = f >> 3, kk = (f & 7) * 4;
      float4 v = *reinterpret_cast<const float4*>(W + (size_t)r * DI + k0 + kk);
      Ws[kk + 0][r] = v.x;
      Ws[kk + 1][r] = v.y;
      Ws[kk + 2][r] = v.z;
      Ws[kk + 3][r] = v.w;
    }
    if (tid < 128) {
      int f = tid + 256;
      int r = f >> 3, kk = (f & 7) * 4;
      float4 v = *reinterpret_cast<const float4*>(W + (size_t)r * DI + k0 + kk);
      Ws[kk + 0][r] = v.x;
      Ws[kk + 1][r] = v.y;
      Ws[kk + 2][r] = v.z;
      Ws[kk + 3][r] = v.w;
    }
    __syncthreads();
#pragma unroll
    for (int k = 0; k < 32; ++k) {
      float a[4], w[3];
#pragma unroll
      for (int i = 0; i < 4; ++i) a[i] = As[k][ty * 4 + i];
#pragma unroll
      for (int j = 0; j < 3; ++j) w[j] = Ws[k][tx * 3 + j];
#pragma unroll
      for (int i = 0; i < 4; ++i)
#pragma unroll
        for (int j = 0; j < 3; ++j) acc[i][j] = fmaf(a[i], w[j], acc[i][j]);
    }
    __syncthreads();
  }
#pragma unroll
  for (int i = 0; i < 4; ++i) {
    int row = bm + ty * 4 + i;
#pragma unroll
    for (int j = 0; j < 3; ++j) {
      int c = tx * 3 + j;
      float* dst = (c < 16) ? DTR : (c < 32) ? BB : CB;
      dst[(size_t)row * 16 + (c & 15)] = acc[i][j];
    }
  }
}

// ---------------- scan pass 1: per-chunk local scan + dA product ----------------
// block: b = blk>>7, r = blk&127, chunk c = r>>1, d = (r&1)*256 + tid.
__global__ __launch_bounds__(256) void scan_pass1(
    const float* __restrict__ UC, const float* __restrict__ DTR,
    const float* __restrict__ Wdt, const float* __restrict__ bdt,
    const float* __restrict__ BB, const float* __restrict__ Alog,
    float* __restrict__ APR, float* __restrict__ HLOC) {
  const int blk = blockIdx.x;
  const int b = blk >> 7;
  const int r = blk & 127;
  const int c = r >> 1;
  const int d = (r & 1) * 256 + threadIdx.x;
  float w[16], A2[16], h[16], ap[16];
  {
    const float4* w4 = reinterpret_cast<const float4*>(Wdt + (size_t)d * 16);
    const float4* a4 = reinterpret_cast<const float4*>(Alog + (size_t)d * 16);
#pragma unroll
    for (int q = 0; q < 4; ++q) {
      float4 v = w4[q];
      w[q * 4] = v.x; w[q * 4 + 1] = v.y; w[q * 4 + 2] = v.z; w[q * 4 + 3] = v.w;
      float4 a = a4[q];
      A2[q * 4]     = -__expf(a.x) * 1.44269504f;
      A2[q * 4 + 1] = -__expf(a.y) * 1.44269504f;
      A2[q * 4 + 2] = -__expf(a.z) * 1.44269504f;
      A2[q * 4 + 3] = -__expf(a.w) * 1.44269504f;
    }
  }
  const float bias = bdt[d];
#pragma unroll
  for (int n = 0; n < 16; ++n) { h[n] = 0.f; ap[n] = 1.f; }
  const int t0 = c * CHT;
#pragma unroll 2
  for (int tt = 0; tt < CHT; ++tt) {
    const size_t row = (size_t)b * LSEQ + (t0 + tt);
    const float4* dtr4 = reinterpret_cast<const float4*>(DTR + row * 16);
    const float4* bb4 = reinterpret_cast<const float4*>(BB + row * 16);
    float4 d0 = dtr4[0], d1 = dtr4[1], d2 = dtr4[2], d3 = dtr4[3];
    float4 b0 = bb4[0], b1 = bb4[1], b2 = bb4[2], b3 = bb4[3];
    float uv = UC[row * DI + d];
    float sdt = bias
      + d0.x * w[0] + d0.y * w[1] + d0.z * w[2] + d0.w * w[3]
      + d1.x * w[4] + d1.y * w[5] + d1.z * w[6] + d1.w * w[7]
      + d2.x * w[8] + d2.y * w[9] + d2.z * w[10] + d2.w * w[11]
      + d3.x * w[12] + d3.y * w[13] + d3.z * w[14] + d3.w * w[15];
    float dtv = softplus_f(sdt);
    float Bn[16] = {b0.x, b0.y, b0.z, b0.w, b1.x, b1.y, b1.z, b1.w,
                    b2.x, b2.y, b2.z, b2.w, b3.x, b3.y, b3.z, b3.w};
    float dtu = dtv * uv;
#pragma unroll
    for (int n = 0; n < 16; ++n) {
      float dA = fast_exp2(dtv * A2[n]);
      ap[n] *= dA;
      h[n] = fmaf(dA, h[n], dtu * Bn[n]);
    }
  }
  const size_t cidx = (((size_t)b * NCH + c) * DI + d) * 16;
  float4* ao = reinterpret_cast<float4*>(APR + cidx);
  float4* ho = reinterpret_cast<float4*>(HLOC + cidx);
#pragma unroll
  for (int q = 0; q < 4; ++q) {
    ao[q] = float4{ap[q * 4], ap[q * 4 + 1], ap[q * 4 + 2], ap[q * 4 + 3]};
    ho[q] = float4{h[q * 4], h[q * 4 + 1], h[q * 4 + 2], h[q * 4 + 3]};
  }
}

// ---------------- scan pass 2: serial carry over chunks ----------------
__global__ __launch_bounds__(256) void scan_pass2(
    const float* __restrict__ APR, float* __restrict__ HLOC) {
  const int tg = blockIdx.x * 256 + threadIdx.x;
  const int b = tg >> 13;
  const int rem = tg & 8191;
  const int d = rem >> 4;
  const int n = rem & 15;
  float hin = 0.f;
  for (int c = 0; c < NCH; ++c) {
    const size_t idx = (((size_t)b * NCH + c) * DI + d) * 16 + n;
    float a = APR[idx];
    float hl = HLOC[idx];
    HLOC[idx] = hin;
    hin = fmaf(a, hin, hl);
  }
}

// ---------------- scan pass 3: seeded replay; Y written as bf16 -> YB ----------
__global__ __launch_bounds__(256) void scan_pass3(
    const float* __restrict__ UC, const float* __restrict__ DTR,
    const float* __restrict__ Wdt, const float* __restrict__ bdt,
    const float* __restrict__ Z, const float* __restrict__ BB,
    const float* __restrict__ CB, const float* __restrict__ Alog,
    const float* __restrict__ Dp, const float* __restrict__ HLOC,
    ushort* __restrict__ YB) {
  const int blk = blockIdx.x;
  const int b = blk >> 7;
  const int r = blk & 127;
  const int c = r >> 1;
  const int d = (r & 1) * 256 + threadIdx.x;
  float w[16], A2[16], h[16];
  {
    const float4* w4 = reinterpret_cast<const float4*>(Wdt + (size_t)d * 16);
    const float4* a4 = reinterpret_cast<const float4*>(Alog + (size_t)d * 16);
#pragma unroll
    for (int q = 0; q < 4; ++q) {
      float4 v = w4[q];
      w[q * 4] = v.x; w[q * 4 + 1] = v.y; w[q * 4 + 2] = v.z; w[q * 4 + 3] = v.w;
      float4 a = a4[q];
      A2[q * 4]     = -__expf(a.x) * 1.44269504f;
      A2[q * 4 + 1] = -__expf(a.y) * 1.44269504f;
      A2[q * 4 + 2] = -__expf(a.z) * 1.44269504f;
      A2[q * 4 + 3] = -__expf(a.w) * 1.44269504f;
    }
  }
  const float bias = bdt[d];
  const float Dd = Dp[d];
  {
    const size_t cidx = (((size_t)b * NCH + c) * DI + d) * 16;
    const float4* hs = reinterpret_cast<const float4*>(HLOC + cidx);
#pragma unroll
    for (int q = 0; q < 4; ++q) {
      float4 v = hs[q];
      h[q * 4] = v.x; h[q * 4 + 1] = v.y; h[q * 4 + 2] = v.z; h[q * 4 + 3] = v.w;
    }
  }
  const int t0 = c * CHT;
#pragma unroll 2
  for (int tt = 0; tt < CHT; ++tt) {
    const size_t row = (size_t)b * LSEQ + (t0 + tt);
    const float4* dtr4 = reinterpret_cast<const float4*>(DTR + row * 16);
    const float4* bb4 = reinterpret_cast<const float4*>(BB + row * 16);
    const float4* cb4 = reinterpret_cast<const float4*>(CB + row * 16);
    float4 d0 = dtr4[0], d1 = dtr4[1], d2 = dtr4[2], d3 = dtr4[3];
    float4 b0 = bb4[0], b1 = bb4[1], b2 = bb4[2], b3 = bb4[3];
    float4 c0 = cb4[0], c1 = cb4[1], c2 = cb4[2], c3 = cb4[3];
    float uv = UC[row * DI + d];
    float zv = Z[row * DI + d];
    float sdt = bias
      + d0.x * w[0] + d0.y * w[1] + d0.z * w[2] + d0.w * w[3]
      + d1.x * w[4] + d1.y * w[5] + d1.z * w[6] + d1.w * w[7]
      + d2.x * w[8] + d2.y * w[9] + d2.z * w[10] + d2.w * w[11]
      + d3.x * w[12] + d3.y * w[13] + d3.z * w[14] + d3.w * w[15];
    float dtv = softplus_f(sdt);
    float Bn[16] = {b0.x, b0.y, b0.z, b0.w, b1.x, b1.y, b1.z, b1.w,
                    b2.x, b2.y, b2.z, b2.w, b3.x, b3.y, b3.z, b3.w};
    float Cn[16] = {c0.x, c0.y, c0.z, c0.w, c1.x, c1.y, c1.z, c1.w,
                    c2.x, c2.y, c2.z, c2.w, c3.x, c3.y, c3.z, c3.w};
    float dtu = dtv * uv;
    float y = 0.f;
#pragma unroll
    for (int n = 0; n < 16; ++n) {
      float dA = fast_exp2(dtv * A2[n]);
      h[n] = fmaf(dA, h[n], dtu * Bn[n]);
      y = fmaf(h[n], Cn[n], y);
    }
    float yo = (y + Dd * uv) * silu_f(zv);
    __hip_bfloat16 hb = __float2bfloat16(yo);
    YB[row * DI + d] = *reinterpret_cast<ushort*>(&hb);
  }
}

// ---------------- LayerNorm in-place ----------------
__global__ __launch_bounds__(256) void ln_kernel(
    float* __restrict__ H, const float* __restrict__ G, const float* __restrict__ Be) {
  const int lane = threadIdx.x & 63;
  const int row = blockIdx.x * 4 + (threadIdx.x >> 6);
  float4 v = *reinterpret_cast<const float4*>(H + (size_t)row * DM + lane * 4);
  float s = v.x + v.y + v.z + v.w;
  float sq = v.x * v.x + v.y * v.y + v.z * v.z + v.w * v.w;
#pragma unroll
  for (int m = 32; m >= 1; m >>= 1) {
    s += __shfl_xor(s, m);
    sq += __shfl_xor(sq, m);
  }
  float mu = s * (1.f / 256.f);
  float var = sq * (1.f / 256.f) - mu * mu;
  float inv = rsqrtf(var + 1e-5f);
  float4 g = *reinterpret_cast<const float4*>(G + lane * 4);
  float4 be = *reinterpret_cast<const float4*>(Be + lane * 4);
  float4 o;
  o.x = (v.x - mu) * inv * g.x + be.x;
  o.y = (v.y - mu) * inv * g.y + be.y;
  o.z = (v.z - mu) * inv * g.z + be.z;
  o.w = (v.w - mu) * inv * g.w + be.w;
  *reinterpret_cast<float4*>(H + (size_t)row * DM + lane * 4) = o;
}

extern "C" void kernel_launch(void* const* d_in, const int* in_sizes, int n_in,
                              void* d_out, int out_size, void* d_ws, size_t ws_size,
                              hipStream_t stream) {
  const float* x = (const float*)d_in[0];
  const float* ln_g = (const float*)d_in[19];
  const float* ln_b = (const float*)d_in[20];
  float* out = (float*)d_out;
  float* ws = (float*)d_ws;

  float* U = ws;                        // TOK*DI fp32 (u; APR/HLOC alias after conv)
  float* Z = U + (size_t)TOK * DI;      // TOK*DI fp32
  float* UC = Z + (size_t)TOK * DI;     // TOK*DI fp32
  float* DTR = UC + (size_t)TOK * DI;   // TOK*16
  float* BB = DTR + (size_t)TOK * 16;
  float* CB = BB + (size_t)TOK * 16;
  float* fend = CB + (size_t)TOK * 16;
  ushort* XB = (ushort*)fend;                     // TOK*256 bf16 (8.4 MB)
  ushort* YB = XB + (size_t)TOK * 256;            // TOK*DI bf16 (16.8 MB)
  ushort* WinB = YB + (size_t)TOK * DI;           // 1024*256 bf16
  ushort* WoutB = WinB + (size_t)1024 * 256;      // 256*512 bf16
  float* APR = U;                                 // alias: 8*64*512*16*4 = 16.77 MB
  float* HLOC = U + (size_t)8 * NCH * DI * NST;   // second 16.77 MB (fits U exactly)

  cvt_f32_bf16<<<(TOK * 256 / 4 + 255) / 256, 256, 0, stream>>>(x, XB, TOK * 256 / 4);

  for (int dir = 0; dir < 2; ++dir) {
    const float* Win = (const float*)d_in[1 + dir * 9];
    const float* cw = (const float*)d_in[2 + dir * 9];
    const float* cb = (const float*)d_in[3 + dir * 9];
    const float* Wx = (const float*)d_in[4 + dir * 9];
    const float* Wdt = (const float*)d_in[5 + dir * 9];
    const float* bdt = (const float*)d_in[6 + dir * 9];
    const float* Alog = (const float*)d_in[7 + dir * 9];
    const float* Dp = (const float*)d_in[8 + dir * 9];
    const float* Wout = (const float*)d_in[9 + dir * 9];

    cvt_f32_bf16<<<256, 256, 0, stream>>>(Win, WinB, 1024 * 256 / 4);
    cvt_f32_bf16<<<128, 256, 0, stream>>>(Wout, WoutB, 256 * 512 / 4);
    gemm_inproj_mfma<<<dim3(8, 128), 256, 0, stream>>>(XB, WinB, U, Z, dir);
    conv_kernel<<<(TOK * DI) / 256, 256, 0, stream>>>(U, cw, cb, UC);
    gemm_xproj<<<TOK / 64, 256, 0, stream>>>(UC, Wx, DTR, BB, CB);
    scan_pass1<<<1024, 256, 0, stream>>>(UC, DTR, Wdt, bdt, BB, Alog, APR, HLOC);
    scan_pass2<<<256, 256, 0, stream>>>(APR, HLOC);
    scan_pass3<<<1024, 256, 0, stream>>>(UC, DTR, Wdt, bdt, Z, BB, CB, Alog, Dp, HLOC, YB);
    gemm_outproj_mfma<<<dim3(4, 128), 256, 0, stream>>>(YB, WoutB, x, out, dir);
  }
  ln_kernel<<<TOK / 4, 256, 0, stream>>>(out, ln_g, ln_b);
}

// Round 15
// 593.384 us; speedup vs baseline: 7.6204x; 1.1006x over previous
//
#include <hip/hip_runtime.h>
#include <hip/hip_bf16.h>
#include <math.h>

// BiMambaBlock: B=8, L=2048, D_MODEL=256, D_INNER=512, N=16, DT_RANK=16, D_CONV=4
// r9: chunked 3-pass scan (850us). r10: bf16-MFMA in/out_proj (674us).
// r11: NCH 64 + unroll2 (653us; occupancy 2x but time ~flat -> latency still exposed).
// r12 (this): explicit software pipeline in pass1/pass3 (load t+1 before compute t,
//             register rotation) + cheap __logf softplus.
//
// Per direction:
//  0) cvt: x -> XB (bf16, once), Win -> WinB, Wout -> WoutB (bf16, per dir)
//  1) in_proj MFMA GEMM (bf16 in, fp32 out): U, Z
//  2) conv4 + silu (fp32): U -> UC
//  3) x_proj GEMM (fp32): UC -> DTR|BB|CB
//  4-6) 3-pass chunked scan (64 chunks x 32 steps); pass3 writes Y bf16 -> YB
//  7) out_proj MFMA GEMM: out[flip] (+)= YB @ WoutB^T (+x residual on dir0)
// Then LayerNorm in-place.
// APR/HLOC alias U (dead after conv): 2 x 16.77 MB = 33.55 MB = U exactly.

#define TOK 16384
#define LSEQ 2048
#define DI 512
#define DM 256
#define NST 16
#define NCH 64
#define CHT 32

typedef __attribute__((ext_vector_type(8))) short bf16x8;
typedef __attribute__((ext_vector_type(4))) float f32x4;

__device__ __forceinline__ float fast_exp2(float x) {
#if defined(__has_builtin)
#if __has_builtin(__builtin_amdgcn_exp2f)
  return __builtin_amdgcn_exp2f(x);
#else
  return exp2f(x);
#endif
#else
  return exp2f(x);
#endif
}

__device__ __forceinline__ float silu_f(float v) {
  return v / (1.f + __expf(-v));
}

// cheap softplus: 2 trans + 2 VALU instead of libm log1pf.
// |err| ~1e-7 rel; for s<-15 underflows to 0 (true value <3e-7) -- negligible.
__device__ __forceinline__ float softplus_f(float s) {
  return (s > 20.f) ? s : __logf(1.f + __expf(s));
}

// ---------------- fp32 -> bf16 conversion (vectorized x4) ----------------
__global__ __launch_bounds__(256) void cvt_f32_bf16(
    const float* __restrict__ in, ushort* __restrict__ out, int n4) {
  int i = blockIdx.x * 256 + threadIdx.x;
  if (i >= n4) return;
  float4 v = *reinterpret_cast<const float4*>(in + (size_t)i * 4);
  __hip_bfloat16 b0 = __float2bfloat16(v.x);
  __hip_bfloat16 b1 = __float2bfloat16(v.y);
  __hip_bfloat16 b2 = __float2bfloat16(v.z);
  __hip_bfloat16 b3 = __float2bfloat16(v.w);
  ushort4 o = {*reinterpret_cast<ushort*>(&b0), *reinterpret_cast<ushort*>(&b1),
               *reinterpret_cast<ushort*>(&b2), *reinterpret_cast<ushort*>(&b3)};
  *reinterpret_cast<ushort4*>(out + (size_t)i * 4) = o;
}

// ---------------- in_proj MFMA: M=16384, N=1024, K=256 ----------------
__global__ __launch_bounds__(256) void gemm_inproj_mfma(
    const ushort* __restrict__ XB, const ushort* __restrict__ WB,
    float* __restrict__ U, float* __restrict__ Z, int dir) {
  const int tid = threadIdx.x;
  const int wid = tid >> 6, lane = tid & 63;
  const int wm = wid >> 1, wn = wid & 1;
  const int bm = blockIdx.y * 128, bn = blockIdx.x * 128;
  const int lrow = lane & 15, kg = lane >> 4;
  f32x4 acc[4][4] = {};
  const ushort* aptr[4];
  const ushort* bptr[4];
#pragma unroll
  for (int mt = 0; mt < 4; ++mt) {
    int row = bm + wm * 64 + mt * 16 + lrow;
    int bb = row >> 11, tp = row & 2047;
    int src = (bb << 11) + (dir ? (2047 - tp) : tp);
    aptr[mt] = XB + (size_t)src * 256 + kg * 8;
  }
#pragma unroll
  for (int nt = 0; nt < 4; ++nt) {
    int col = bn + wn * 64 + nt * 16 + lrow;
    bptr[nt] = WB + (size_t)col * 256 + kg * 8;
  }
  for (int k0 = 0; k0 < 256; k0 += 32) {
    bf16x8 a[4], b[4];
#pragma unroll
    for (int mt = 0; mt < 4; ++mt)
      a[mt] = *reinterpret_cast<const bf16x8*>(aptr[mt] + k0);
#pragma unroll
    for (int nt = 0; nt < 4; ++nt)
      b[nt] = *reinterpret_cast<const bf16x8*>(bptr[nt] + k0);
#pragma unroll
    for (int mt = 0; mt < 4; ++mt)
#pragma unroll
      for (int nt = 0; nt < 4; ++nt)
        acc[mt][nt] = __builtin_amdgcn_mfma_f32_16x16x32_bf16(a[mt], b[nt], acc[mt][nt], 0, 0, 0);
  }
#pragma unroll
  for (int mt = 0; mt < 4; ++mt) {
#pragma unroll
    for (int r = 0; r < 4; ++r) {
      int row = bm + wm * 64 + mt * 16 + kg * 4 + r;
#pragma unroll
      for (int nt = 0; nt < 4; ++nt) {
        int col = bn + wn * 64 + nt * 16 + lrow;
        float v = acc[mt][nt][r];
        if (col < DI) U[(size_t)row * DI + col] = v;
        else Z[(size_t)row * DI + (col - DI)] = v;
      }
    }
  }
}

// ---------------- out_proj MFMA: M=16384, N=256, K=512 ----------------
__global__ __launch_bounds__(256) void gemm_outproj_mfma(
    const ushort* __restrict__ YB, const ushort* __restrict__ WB,
    const float* __restrict__ X, float* __restrict__ Out, int dir) {
  const int tid = threadIdx.x;
  const int wid = tid >> 6, lane = tid & 63;
  const int wm = wid >> 1, wn = wid & 1;
  const int bm = blockIdx.y * 128, bn = blockIdx.x * 64;
  const int lrow = lane & 15, kg = lane >> 4;
  f32x4 acc[4][2] = {};
  const ushort* aptr[4];
  const ushort* bptr[2];
#pragma unroll
  for (int mt = 0; mt < 4; ++mt) {
    int row = bm + wm * 64 + mt * 16 + lrow;
    aptr[mt] = YB + (size_t)row * DI + kg * 8;
  }
#pragma unroll
  for (int nt = 0; nt < 2; ++nt) {
    int col = bn + wn * 32 + nt * 16 + lrow;
    bptr[nt] = WB + (size_t)col * DI + kg * 8;
  }
  for (int k0 = 0; k0 < 512; k0 += 32) {
    bf16x8 a[4], b[2];
#pragma unroll
    for (int mt = 0; mt < 4; ++mt)
      a[mt] = *reinterpret_cast<const bf16x8*>(aptr[mt] + k0);
#pragma unroll
    for (int nt = 0; nt < 2; ++nt)
      b[nt] = *reinterpret_cast<const bf16x8*>(bptr[nt] + k0);
#pragma unroll
    for (int mt = 0; mt < 4; ++mt)
#pragma unroll
      for (int nt = 0; nt < 2; ++nt)
        acc[mt][nt] = __builtin_amdgcn_mfma_f32_16x16x32_bf16(a[mt], b[nt], acc[mt][nt], 0, 0, 0);
  }
#pragma unroll
  for (int mt = 0; mt < 4; ++mt) {
#pragma unroll
    for (int r = 0; r < 4; ++r) {
      int row = bm + wm * 64 + mt * 16 + kg * 4 + r;
      int bb = row >> 11, tp = row & 2047;
      int orow = (bb << 11) + (dir ? (2047 - tp) : tp);
#pragma unroll
      for (int nt = 0; nt < 2; ++nt) {
        int col = bn + wn * 32 + nt * 16 + lrow;
        float v = acc[mt][nt][r];
        size_t oi = (size_t)orow * DM + col;
        if (dir == 0) Out[oi] = v + X[oi];
        else Out[oi] += v;
      }
    }
  }
}

// ---------------- causal depthwise conv4 + bias + silu ----------------
__global__ __launch_bounds__(256) void conv_kernel(
    const float* __restrict__ U, const float* __restrict__ CW,
    const float* __restrict__ CB, float* __restrict__ UC) {
  int idx = blockIdx.x * 256 + threadIdx.x;
  int tl = idx >> 9, d = idx & 511;
  int tp = tl & 2047;
  float4 w4 = *reinterpret_cast<const float4*>(CW + (size_t)d * 4);
  float u3 = U[idx];
  float u2 = (tp >= 1) ? U[idx - 512] : 0.f;
  float u1 = (tp >= 2) ? U[idx - 1024] : 0.f;
  float u0 = (tp >= 3) ? U[idx - 1536] : 0.f;
  float acc = CB[d] + w4.x * u0 + w4.y * u1 + w4.z * u2 + w4.w * u3;
  UC[idx] = silu_f(acc);
}

// ---------------- x_proj GEMM: M=16384, N=48, K=512 (fp32) ----------------
__global__ __launch_bounds__(256) void gemm_xproj(
    const float* __restrict__ UC, const float* __restrict__ W,
    float* __restrict__ DTR, float* __restrict__ BB, float* __restrict__ CB) {
  __shared__ float As[32][68];
  __shared__ float Ws[32][52];
  const int tid = threadIdx.x;
  const int bm = blockIdx.x * 64;
  const int tx = tid & 15, ty = tid >> 4;
  float acc[4][3] = {};
  for (int k0 = 0; k0 < 512; k0 += 32) {
#pragma unroll
    for (int h = 0; h < 2; ++h) {
      int f = tid + h * 256;
      int r = f >> 3, kk = (f & 7) * 4;
      float4 v = *reinterpret_cast<const float4*>(UC + (size_t)(bm + r) * DI + k0 + kk);
      As[kk + 0][r] = v.x;
      As[kk + 1][r] = v.y;
      As[kk + 2][r] = v.z;
      As[kk + 3][r] = v.w;
    }
    {
      int f = tid;
      int r = f >> 3, kk = (f & 7) * 4;
      float4 v = *reinterpret_cast<const float4*>(W + (size_t)r * DI + k0 + kk);
      Ws[kk + 0][r] = v.x;
      Ws[kk + 1][r] = v.y;
      Ws[kk + 2][r] = v.z;
      Ws[kk + 3][r] = v.w;
    }
    if (tid < 128) {
      int f = tid + 256;
      int r = f >> 3, kk = (f & 7) * 4;
      float4 v = *reinterpret_cast<const float4*>(W + (size_t)r * DI + k0 + kk);
      Ws[kk + 0][r] = v.x;
      Ws[kk + 1][r] = v.y;
      Ws[kk + 2][r] = v.z;
      Ws[kk + 3][r] = v.w;
    }
    __syncthreads();
#pragma unroll
    for (int k = 0; k < 32; ++k) {
      float a[4], w[3];
#pragma unroll
      for (int i = 0; i < 4; ++i) a[i] = As[k][ty * 4 + i];
#pragma unroll
      for (int j = 0; j < 3; ++j) w[j] = Ws[k][tx * 3 + j];
#pragma unroll
      for (int i = 0; i < 4; ++i)
#pragma unroll
        for (int j = 0; j < 3; ++j) acc[i][j] = fmaf(a[i], w[j], acc[i][j]);
    }
    __syncthreads();
  }
#pragma unroll
  for (int i = 0; i < 4; ++i) {
    int row = bm + ty * 4 + i;
#pragma unroll
    for (int j = 0; j < 3; ++j) {
      int c = tx * 3 + j;
      float* dst = (c < 16) ? DTR : (c < 32) ? BB : CB;
      dst[(size_t)row * 16 + (c & 15)] = acc[i][j];
    }
  }
}

// ---------------- scan pass 1: per-chunk local scan + dA product ----------------
// Explicit software pipeline: issue step t+1's loads before computing step t.
__global__ __launch_bounds__(256) void scan_pass1(
    const float* __restrict__ UC, const float* __restrict__ DTR,
    const float* __restrict__ Wdt, const float* __restrict__ bdt,
    const float* __restrict__ BB, const float* __restrict__ Alog,
    float* __restrict__ APR, float* __restrict__ HLOC) {
  const int blk = blockIdx.x;
  const int b = blk >> 7;
  const int r = blk & 127;
  const int c = r >> 1;
  const int d = (r & 1) * 256 + threadIdx.x;
  float w[16], A2[16], h[16], ap[16];
  {
    const float4* w4 = reinterpret_cast<const float4*>(Wdt + (size_t)d * 16);
    const float4* a4 = reinterpret_cast<const float4*>(Alog + (size_t)d * 16);
#pragma unroll
    for (int q = 0; q < 4; ++q) {
      float4 v = w4[q];
      w[q * 4] = v.x; w[q * 4 + 1] = v.y; w[q * 4 + 2] = v.z; w[q * 4 + 3] = v.w;
      float4 a = a4[q];
      A2[q * 4]     = -__expf(a.x) * 1.44269504f;
      A2[q * 4 + 1] = -__expf(a.y) * 1.44269504f;
      A2[q * 4 + 2] = -__expf(a.z) * 1.44269504f;
      A2[q * 4 + 3] = -__expf(a.w) * 1.44269504f;
    }
  }
  const float bias = bdt[d];
#pragma unroll
  for (int n = 0; n < 16; ++n) { h[n] = 0.f; ap[n] = 1.f; }
  size_t row = (size_t)b * LSEQ + c * CHT;
  // prologue: load step 0
  float4 nd0, nd1, nd2, nd3, nb0, nb1, nb2, nb3;
  float nuv;
  {
    const float4* p = reinterpret_cast<const float4*>(DTR + row * 16);
    nd0 = p[0]; nd1 = p[1]; nd2 = p[2]; nd3 = p[3];
    const float4* q = reinterpret_cast<const float4*>(BB + row * 16);
    nb0 = q[0]; nb1 = q[1]; nb2 = q[2]; nb3 = q[3];
    nuv = UC[row * DI + d];
  }
  for (int tt = 0; tt < CHT; ++tt) {
    float4 d0 = nd0, d1 = nd1, d2 = nd2, d3 = nd3;
    float4 b0 = nb0, b1 = nb1, b2 = nb2, b3 = nb3;
    float uv = nuv;
    if (tt + 1 < CHT) {
      const size_t r2 = row + 1;
      const float4* p = reinterpret_cast<const float4*>(DTR + r2 * 16);
      nd0 = p[0]; nd1 = p[1]; nd2 = p[2]; nd3 = p[3];
      const float4* q = reinterpret_cast<const float4*>(BB + r2 * 16);
      nb0 = q[0]; nb1 = q[1]; nb2 = q[2]; nb3 = q[3];
      nuv = UC[r2 * DI + d];
    }
    float sdt = bias
      + d0.x * w[0] + d0.y * w[1] + d0.z * w[2] + d0.w * w[3]
      + d1.x * w[4] + d1.y * w[5] + d1.z * w[6] + d1.w * w[7]
      + d2.x * w[8] + d2.y * w[9] + d2.z * w[10] + d2.w * w[11]
      + d3.x * w[12] + d3.y * w[13] + d3.z * w[14] + d3.w * w[15];
    float dtv = softplus_f(sdt);
    float Bn[16] = {b0.x, b0.y, b0.z, b0.w, b1.x, b1.y, b1.z, b1.w,
                    b2.x, b2.y, b2.z, b2.w, b3.x, b3.y, b3.z, b3.w};
    float dtu = dtv * uv;
#pragma unroll
    for (int n = 0; n < 16; ++n) {
      float dA = fast_exp2(dtv * A2[n]);
      ap[n] *= dA;
      h[n] = fmaf(dA, h[n], dtu * Bn[n]);
    }
    ++row;
  }
  const size_t cidx = (((size_t)b * NCH + c) * DI + d) * 16;
  float4* ao = reinterpret_cast<float4*>(APR + cidx);
  float4* ho = reinterpret_cast<float4*>(HLOC + cidx);
#pragma unroll
  for (int q = 0; q < 4; ++q) {
    ao[q] = float4{ap[q * 4], ap[q * 4 + 1], ap[q * 4 + 2], ap[q * 4 + 3]};
    ho[q] = float4{h[q * 4], h[q * 4 + 1], h[q * 4 + 2], h[q * 4 + 3]};
  }
}

// ---------------- scan pass 2: serial carry over chunks ----------------
__global__ __launch_bounds__(256) void scan_pass2(
    const float* __restrict__ APR, float* __restrict__ HLOC) {
  const int tg = blockIdx.x * 256 + threadIdx.x;
  const int b = tg >> 13;
  const int rem = tg & 8191;
  const int d = rem >> 4;
  const int n = rem & 15;
  float hin = 0.f;
  for (int c = 0; c < NCH; ++c) {
    const size_t idx = (((size_t)b * NCH + c) * DI + d) * 16 + n;
    float a = APR[idx];
    float hl = HLOC[idx];
    HLOC[idx] = hin;
    hin = fmaf(a, hin, hl);
  }
}

// ---------------- scan pass 3: seeded replay; software-pipelined ----------
__global__ __launch_bounds__(256) void scan_pass3(
    const float* __restrict__ UC, const float* __restrict__ DTR,
    const float* __restrict__ Wdt, const float* __restrict__ bdt,
    const float* __restrict__ Z, const float* __restrict__ BB,
    const float* __restrict__ CB, const float* __restrict__ Alog,
    const float* __restrict__ Dp, const float* __restrict__ HLOC,
    ushort* __restrict__ YB) {
  const int blk = blockIdx.x;
  const int b = blk >> 7;
  const int r = blk & 127;
  const int c = r >> 1;
  const int d = (r & 1) * 256 + threadIdx.x;
  float w[16], A2[16], h[16];
  {
    const float4* w4 = reinterpret_cast<const float4*>(Wdt + (size_t)d * 16);
    const float4* a4 = reinterpret_cast<const float4*>(Alog + (size_t)d * 16);
#pragma unroll
    for (int q = 0; q < 4; ++q) {
      float4 v = w4[q];
      w[q * 4] = v.x; w[q * 4 + 1] = v.y; w[q * 4 + 2] = v.z; w[q * 4 + 3] = v.w;
      float4 a = a4[q];
      A2[q * 4]     = -__expf(a.x) * 1.44269504f;
      A2[q * 4 + 1] = -__expf(a.y) * 1.44269504f;
      A2[q * 4 + 2] = -__expf(a.z) * 1.44269504f;
      A2[q * 4 + 3] = -__expf(a.w) * 1.44269504f;
    }
  }
  const float bias = bdt[d];
  const float Dd = Dp[d];
  {
    const size_t cidx = (((size_t)b * NCH + c) * DI + d) * 16;
    const float4* hs = reinterpret_cast<const float4*>(HLOC + cidx);
#pragma unroll
    for (int q = 0; q < 4; ++q) {
      float4 v = hs[q];
      h[q * 4] = v.x; h[q * 4 + 1] = v.y; h[q * 4 + 2] = v.z; h[q * 4 + 3] = v.w;
    }
  }
  size_t row = (size_t)b * LSEQ + c * CHT;
  // prologue: load step 0
  float4 nd0, nd1, nd2, nd3, nb0, nb1, nb2, nb3, nc0, nc1, nc2, nc3;
  float nuv, nzv;
  {
    const float4* p = reinterpret_cast<const float4*>(DTR + row * 16);
    nd0 = p[0]; nd1 = p[1]; nd2 = p[2]; nd3 = p[3];
    const float4* q = reinterpret_cast<const float4*>(BB + row * 16);
    nb0 = q[0]; nb1 = q[1]; nb2 = q[2]; nb3 = q[3];
    const float4* s = reinterpret_cast<const float4*>(CB + row * 16);
    nc0 = s[0]; nc1 = s[1]; nc2 = s[2]; nc3 = s[3];
    nuv = UC[row * DI + d];
    nzv = Z[row * DI + d];
  }
  for (int tt = 0; tt < CHT; ++tt) {
    float4 d0 = nd0, d1 = nd1, d2 = nd2, d3 = nd3;
    float4 b0 = nb0, b1 = nb1, b2 = nb2, b3 = nb3;
    float4 c0 = nc0, c1 = nc1, c2 = nc2, c3 = nc3;
    float uv = nuv, zv = nzv;
    if (tt + 1 < CHT) {
      const size_t r2 = row + 1;
      const float4* p = reinterpret_cast<const float4*>(DTR + r2 * 16);
      nd0 = p[0]; nd1 = p[1]; nd2 = p[2]; nd3 = p[3];
      const float4* q = reinterpret_cast<const float4*>(BB + r2 * 16);
      nb0 = q[0]; nb1 = q[1]; nb2 = q[2]; nb3 = q[3];
      const float4* s = reinterpret_cast<const float4*>(CB + r2 * 16);
      nc0 = s[0]; nc1 = s[1]; nc2 = s[2]; nc3 = s[3];
      nuv = UC[r2 * DI + d];
      nzv = Z[r2 * DI + d];
    }
    float sdt = bias
      + d0.x * w[0] + d0.y * w[1] + d0.z * w[2] + d0.w * w[3]
      + d1.x * w[4] + d1.y * w[5] + d1.z * w[6] + d1.w * w[7]
      + d2.x * w[8] + d2.y * w[9] + d2.z * w[10] + d2.w * w[11]
      + d3.x * w[12] + d3.y * w[13] + d3.z * w[14] + d3.w * w[15];
    float dtv = softplus_f(sdt);
    float Bn[16] = {b0.x, b0.y, b0.z, b0.w, b1.x, b1.y, b1.z, b1.w,
                    b2.x, b2.y, b2.z, b2.w, b3.x, b3.y, b3.z, b3.w};
    float Cn[16] = {c0.x, c0.y, c0.z, c0.w, c1.x, c1.y, c1.z, c1.w,
                    c2.x, c2.y, c2.z, c2.w, c3.x, c3.y, c3.z, c3.w};
    float dtu = dtv * uv;
    float y = 0.f;
#pragma unroll
    for (int n = 0; n < 16; ++n) {
      float dA = fast_exp2(dtv * A2[n]);
      h[n] = fmaf(dA, h[n], dtu * Bn[n]);
      y = fmaf(h[n], Cn[n], y);
    }
    float yo = (y + Dd * uv) * silu_f(zv);
    __hip_bfloat16 hb = __float2bfloat16(yo);
    YB[row * DI + d] = *reinterpret_cast<ushort*>(&hb);
    ++row;
  }
}

// ---------------- LayerNorm in-place ----------------
__global__ __launch_bounds__(256) void ln_kernel(
    float* __restrict__ H, const float* __restrict__ G, const float* __restrict__ Be) {
  const int lane = threadIdx.x & 63;
  const int row = blockIdx.x * 4 + (threadIdx.x >> 6);
  float4 v = *reinterpret_cast<const float4*>(H + (size_t)row * DM + lane * 4);
  float s = v.x + v.y + v.z + v.w;
  float sq = v.x * v.x + v.y * v.y + v.z * v.z + v.w * v.w;
#pragma unroll
  for (int m = 32; m >= 1; m >>= 1) {
    s += __shfl_xor(s, m);
    sq += __shfl_xor(sq, m);
  }
  float mu = s * (1.f / 256.f);
  float var = sq * (1.f / 256.f) - mu * mu;
  float inv = rsqrtf(var + 1e-5f);
  float4 g = *reinterpret_cast<const float4*>(G + lane * 4);
  float4 be = *reinterpret_cast<const float4*>(Be + lane * 4);
  float4 o;
  o.x = (v.x - mu) * inv * g.x + be.x;
  o.y = (v.y - mu) * inv * g.y + be.y;
  o.z = (v.z - mu) * inv * g.z + be.z;
  o.w = (v.w - mu) * inv * g.w + be.w;
  *reinterpret_cast<float4*>(H + (size_t)row * DM + lane * 4) = o;
}

extern "C" void kernel_launch(void* const* d_in, const int* in_sizes, int n_in,
                              void* d_out, int out_size, void* d_ws, size_t ws_size,
                              hipStream_t stream) {
  const float* x = (const float*)d_in[0];
  const float* ln_g = (const float*)d_in[19];
  const float* ln_b = (const float*)d_in[20];
  float* out = (float*)d_out;
  float* ws = (float*)d_ws;

  float* U = ws;                        // TOK*DI fp32 (u; APR/HLOC alias after conv)
  float* Z = U + (size_t)TOK * DI;      // TOK*DI fp32
  float* UC = Z + (size_t)TOK * DI;     // TOK*DI fp32
  float* DTR = UC + (size_t)TOK * DI;   // TOK*16
  float* BB = DTR + (size_t)TOK * 16;
  float* CB = BB + (size_t)TOK * 16;
  float* fend = CB + (size_t)TOK * 16;
  ushort* XB = (ushort*)fend;                     // TOK*256 bf16 (8.4 MB)
  ushort* YB = XB + (size_t)TOK * 256;            // TOK*DI bf16 (16.8 MB)
  ushort* WinB = YB + (size_t)TOK * DI;           // 1024*256 bf16
  ushort* WoutB = WinB + (size_t)1024 * 256;      // 256*512 bf16
  float* APR = U;                                 // alias: 8*64*512*16*4 = 16.77 MB
  float* HLOC = U + (size_t)8 * NCH * DI * NST;   // second 16.77 MB (fits U exactly)

  cvt_f32_bf16<<<(TOK * 256 / 4 + 255) / 256, 256, 0, stream>>>(x, XB, TOK * 256 / 4);

  for (int dir = 0; dir < 2; ++dir) {
    const float* Win = (const float*)d_in[1 + dir * 9];
    const float* cw = (const float*)d_in[2 + dir * 9];
    const float* cb = (const float*)d_in[3 + dir * 9];
    const float* Wx = (const float*)d_in[4 + dir * 9];
    const float* Wdt = (const float*)d_in[5 + dir * 9];
    const float* bdt = (const float*)d_in[6 + dir * 9];
    const float* Alog = (const float*)d_in[7 + dir * 9];
    const float* Dp = (const float*)d_in[8 + dir * 9];
    const float* Wout = (const float*)d_in[9 + dir * 9];

    cvt_f32_bf16<<<256, 256, 0, stream>>>(Win, WinB, 1024 * 256 / 4);
    cvt_f32_bf16<<<128, 256, 0, stream>>>(Wout, WoutB, 256 * 512 / 4);
    gemm_inproj_mfma<<<dim3(8, 128), 256, 0, stream>>>(XB, WinB, U, Z, dir);
    conv_kernel<<<(TOK * DI) / 256, 256, 0, stream>>>(U, cw, cb, UC);
    gemm_xproj<<<TOK / 64, 256, 0, stream>>>(UC, Wx, DTR, BB, CB);
    scan_pass1<<<1024, 256, 0, stream>>>(UC, DTR, Wdt, bdt, BB, Alog, APR, HLOC);
    scan_pass2<<<256, 256, 0, stream>>>(APR, HLOC);
    scan_pass3<<<1024, 256, 0, stream>>>(UC, DTR, Wdt, bdt, Z, BB, CB, Alog, Dp, HLOC, YB);
    gemm_outproj_mfma<<<dim3(4, 128), 256, 0, stream>>>(YB, WoutB, x, out, dir);
  }
  ln_kernel<<<TOK / 4, 256, 0, stream>>>(out, ln_g, ln_b);
}